// Round 1
// baseline (405.686 us; speedup 1.0000x reference)
//
#include <hip/hip_runtime.h>
#include <hip/hip_bf16.h>

#define N_NODES 100000
#define N_EDGES 1600000
#define HID 64
#define OUT_CH 32

// Deterministic radix partition into dst buckets. Zero global atomics
// (R5: contended global cursors serialize device-wide at ~6 ns/atomic).
// R12 lesson: don't fuse fat-LDS GEMM onto the latency-bound gather.
#define NB 196           // ceil(100000/512) buckets of 512 consecutive dst nodes
#define P 1024           // partition blocks
#define EPP ((N_EDGES + P - 1) / P)   // 1563 edges per block
#define BKCAP 10240      // LDS csr staging cap (bucket mean 8192, sigma ~90)
#define SAP 66           // bf16 tile pitch for head (conflict-free)
#define MP 72            // bf16 tile pitch for MFMA layer (16B-aligned rows)

// Channel-chunked feature layout: features stored as [4][N_NODES][16] bf16.
// Each 16-channel chunk is 3.2 MB -> fits a 4 MB per-XCD L2, so a
// chunk-phased gather reads ~100% from L2 instead of Infinity Cache.
#define CS (N_NODES * 16)        // ushorts per chunk (3.2 MB)
#define GB_PER_CHUNK 6250        // gather blocks per chunk phase (16 nodes/block)

typedef unsigned short ushort_t;
typedef short bf16x8 __attribute__((ext_vector_type(8)));
typedef float f32x4 __attribute__((ext_vector_type(4)));

// bf16 helpers (RNE)
__device__ __forceinline__ ushort_t f2b(float f) {
    union { float f; unsigned u; } un; un.f = f;
    unsigned r = un.u + 0x7FFF + ((un.u >> 16) & 1);
    return (ushort_t)(r >> 16);
}
__device__ __forceinline__ float b2f(ushort_t u) {
    union { unsigned u; float f; } un; un.u = ((unsigned)u) << 16;
    return un.f;
}
__device__ __forceinline__ float blo(unsigned u) {
    union { unsigned u; float f; } un; un.u = u << 16; return un.f;
}
__device__ __forceinline__ float bhi(unsigned u) {
    union { unsigned u; float f; } un; un.u = u & 0xFFFF0000u; return un.f;
}

__device__ __forceinline__ int get_dst(const int* __restrict__ ei, int is64, int e) {
    return is64 ? ((const int2*)ei)[N_EDGES + e].x : ei[N_EDGES + e];
}
__device__ __forceinline__ int get_src(const int* __restrict__ ei, int is64, int e) {
    return is64 ? ((const int2*)ei)[e].x : ei[e];
}

// inline edge-dtype probe: int64 => odd 32-bit words all 0 (first wave)
__device__ __forceinline__ void detect_is64(const int* __restrict__ ei,
                                            int* __restrict__ sflag, int tid) {
    if (tid < 64) {
        int v = ei[2 * tid + 1];
        unsigned long long ball = __ballot(v == 0);
        if (tid == 0) *sflag = (ball == ~0ull) ? 1 : 0;
    }
}

// ---- convert x -> bf16 CHUNKED layout + bucket histograms (blocks <P) -----
#define CONV_BLOCKS ((N_NODES * HID / 4) / 256)   // 6250
__global__ void __launch_bounds__(256) convhist_kernel(
        const float* __restrict__ x, ushort_t* __restrict__ xb,
        const int* __restrict__ ei, int* __restrict__ histG) {
    int i = blockIdx.x * 256 + threadIdx.x;
    if (i < N_NODES * HID / 4) {
        float4 v = ((const float4*)x)[i];
        ushort4 o;
        o.x = f2b(v.x); o.y = f2b(v.y); o.z = f2b(v.z); o.w = f2b(v.w);
        // i covers channels 4g..4g+3 of node i>>4; chunk c = g>>2.
        int node = i >> 4, g = i & 15, c = g >> 2, pos = g & 3;
        ((ushort4*)(xb + (size_t)c * CS))[node * 4 + pos] = o;
    }
    if (blockIdx.x >= P) return;
    __shared__ int sflag;
    __shared__ int lh[NB];
    int tid = threadIdx.x;
    detect_is64(ei, &sflag, tid);
    for (int k = tid; k < NB; k += 256) lh[k] = 0;
    __syncthreads();
    int is64 = sflag;
    int e0 = blockIdx.x * EPP;
    int e1 = min(e0 + EPP, N_EDGES);
    for (int e = e0 + tid; e < e1; e += 256) {
        int d = get_dst(ei, is64, e);
        atomicAdd(&lh[d >> 9], 1);
    }
    __syncthreads();
    for (int k = tid; k < NB; k += 256) histG[k * P + blockIdx.x] = lh[k];
}

// ---- per-bucket exclusive scan over P block-counts (4 elems/thread) -------
__global__ void __launch_bounds__(256) scan_kernel(int* __restrict__ histG,
                                                   int* __restrict__ btot) {
    __shared__ int ps[256];
    int b = blockIdx.x;
    int tid = threadIdx.x;
    int base4 = b * P + 4 * tid;
    int v0 = histG[base4], v1 = histG[base4 + 1], v2 = histG[base4 + 2], v3 = histG[base4 + 3];
    int pv = v0 + v1 + v2 + v3;
    ps[tid] = pv;
    __syncthreads();
    for (int d = 1; d < 256; d <<= 1) {
        int t = (tid >= d) ? ps[tid - d] : 0;
        __syncthreads();
        ps[tid] += t;
        __syncthreads();
    }
    int e = ps[tid] - pv;
    histG[base4] = e; e += v0;
    histG[base4 + 1] = e; e += v1;
    histG[base4 + 2] = e; e += v2;
    histG[base4 + 3] = e;
    if (tid == 255) btot[b] = ps[255];
}

// ---- place records at deterministic offsets (LDS cursors only) ------------
// Bucket bases from local 196-wide scan of btot. record = (dst&511)<<17 | src
__global__ void __launch_bounds__(256) place_kernel(
        const int* __restrict__ ei, const int* __restrict__ histG,
        const int* __restrict__ btot, int* __restrict__ bkt) {
    __shared__ int lcur[NB];
    __shared__ int ss[256];
    __shared__ int sflag;
    int tid = threadIdx.x;
    detect_is64(ei, &sflag, tid);
    int v = (tid < NB) ? btot[tid] : 0;
    ss[tid] = v;
    __syncthreads();
    for (int d = 1; d < 256; d <<= 1) {
        int t = (tid >= d) ? ss[tid - d] : 0;
        __syncthreads();
        ss[tid] += t;
        __syncthreads();
    }
    if (tid < NB) lcur[tid] = (ss[tid] - v) + histG[tid * P + blockIdx.x];
    __syncthreads();
    int is64 = sflag;
    int e0 = blockIdx.x * EPP;
    int e1 = min(e0 + EPP, N_EDGES);
    for (int e = e0 + tid; e < e1; e += 256) {
        int s = get_src(ei, is64, e);
        int d = get_dst(ei, is64, e);
        int val = ((d & 511) << 17) | s;
        int p = atomicAdd(&lcur[d >> 9], 1);
        bkt[p] = val;
    }
}

// ---- per-bucket csr build in LDS + packed off|deg -------------------------
// offpk[n] = (abs_off & 0x1FFFFF) | (deg << 21); bucket base from local scan.
__global__ void __launch_bounds__(256) bucket_fill_kernel(
        const int* __restrict__ btot, const int* __restrict__ bkt,
        int* __restrict__ csr, unsigned int* __restrict__ offpk) {
    __shared__ int lcnt[512];
    __shared__ int loff[512];
    __shared__ int lcur[512];
    __shared__ int ps[256];
    __shared__ int scsr[BKCAP];
    __shared__ int sbase;
    int b = blockIdx.x;
    int tid = threadIdx.x;
    int m = btot[b];
    int vb = (tid < NB) ? btot[tid] : 0;
    ps[tid] = vb;
    __syncthreads();
    for (int d = 1; d < 256; d <<= 1) {
        int t = (tid >= d) ? ps[tid - d] : 0;
        __syncthreads();
        ps[tid] += t;
        __syncthreads();
    }
    if (tid == b) sbase = ps[tid] - vb;   // exclusive prefix at b
    __syncthreads();
    int base = sbase;
    int n0 = b << 9;
    int nn = min(512, N_NODES - n0);

    lcnt[tid] = 0;
    lcnt[tid + 256] = 0;
    __syncthreads();
    for (int i = tid; i < m; i += 256) atomicAdd(&lcnt[bkt[base + i] >> 17], 1);
    __syncthreads();
    int a0 = lcnt[2 * tid], a1 = lcnt[2 * tid + 1];
    int pv = a0 + a1;
    ps[tid] = pv;
    __syncthreads();
    for (int d = 1; d < 256; d <<= 1) {
        int t = (tid >= d) ? ps[tid - d] : 0;
        __syncthreads();
        ps[tid] += t;
        __syncthreads();
    }
    int excl = ps[tid] - pv;
    loff[2 * tid] = excl;
    loff[2 * tid + 1] = excl + a0;
    lcur[2 * tid] = excl;
    lcur[2 * tid + 1] = excl + a0;
    __syncthreads();
    bool fit = (m <= BKCAP);
    for (int i = tid; i < m; i += 256) {
        int val = bkt[base + i];
        int dl = val >> 17;
        int p = atomicAdd(&lcur[dl], 1);
        if (fit) scsr[p] = val & 0x1FFFF;
        else csr[base + p] = val & 0x1FFFF;
    }
    __syncthreads();
    if (fit)
        for (int i = tid; i < m; i += 256) csr[base + i] = scsr[i];
    for (int i = tid; i < nn; i += 256)
        offpk[n0 + i] = (unsigned int)((base + loff[i]) | (lcnt[i] << 21));
}

// ---- gather: chunk-phased, L2-resident --------------------------------
// Phase c (blocks [c*6250, (c+1)*6250)) reads ONLY chunk c (3.2 MB ->
// per-XCD L2 resident; dispatch order paces phases). Per wave: 4 nodes
// (16 lanes each), 4 lanes x int2 = 32B per edge, 16 edges/node in
// flight. csr loads are per-lane clamped+unpredicated (no shfl dep
// chain) and nontemporal (don't evict the resident chunk).
__global__ void __launch_bounds__(256) gather_kernel(
        const ushort_t* __restrict__ hb, const unsigned int* __restrict__ offpk,
        const int* __restrict__ csr, ushort_t* __restrict__ aggb) {
    int bid = blockIdx.x;
    int c = bid / GB_PER_CHUNK;
    int nb = bid - c * GB_PER_CHUNK;
    int tid = threadIdx.x;
    int o = tid & 63;
    int node = nb * 16 + (tid >> 6) * 4 + (o >> 4);   // 6250*16 = 100000 exact
    int s = (o >> 2) & 3;      // edge slot within node
    int p = o & 3;             // channel-quad within chunk
    unsigned int v = offpk[node];
    int off = (int)(v & 0x1FFFFFu);
    int cnt = (int)(v >> 21);
    const ushort_t* fc = hb + (size_t)c * CS;
    float a0 = 0.f, a1 = 0.f, a2 = 0.f, a3 = 0.f;
    int m = (cnt + 15) >> 4;
    m = max(m, __shfl_xor(m, 16));
    m = max(m, __shfl_xor(m, 32));   // max iters over the wave's 4 nodes
    int cl = max(cnt - 1, 0);
    for (int t = 0; t < m; ++t) {
        int e = t * 16 + s;
        int i0 = __builtin_nontemporal_load(csr + off + min(e, cl));
        int i1 = __builtin_nontemporal_load(csr + off + min(e + 4, cl));
        int i2 = __builtin_nontemporal_load(csr + off + min(e + 8, cl));
        int i3 = __builtin_nontemporal_load(csr + off + min(e + 12, cl));
        int2 u0 = ((const int2*)(fc + (size_t)i0 * 16))[p];
        int2 u1 = ((const int2*)(fc + (size_t)i1 * 16))[p];
        int2 u2 = ((const int2*)(fc + (size_t)i2 * 16))[p];
        int2 u3 = ((const int2*)(fc + (size_t)i3 * 16))[p];
        if (e >= cnt)      { u0.x = 0; u0.y = 0; }
        if (e + 4 >= cnt)  { u1.x = 0; u1.y = 0; }
        if (e + 8 >= cnt)  { u2.x = 0; u2.y = 0; }
        if (e + 12 >= cnt) { u3.x = 0; u3.y = 0; }
        a0 += (blo(u0.x) + blo(u1.x)) + (blo(u2.x) + blo(u3.x));
        a1 += (bhi(u0.x) + bhi(u1.x)) + (bhi(u2.x) + bhi(u3.x));
        a2 += (blo(u0.y) + blo(u1.y)) + (blo(u2.y) + blo(u3.y));
        a3 += (bhi(u0.y) + bhi(u1.y)) + (bhi(u2.y) + bhi(u3.y));
    }
    // reduce over edge slot s (lane bits 2..3); stays within the 16-lane node group
    a0 += __shfl_xor(a0, 4); a0 += __shfl_xor(a0, 8);
    a1 += __shfl_xor(a1, 4); a1 += __shfl_xor(a1, 8);
    a2 += __shfl_xor(a2, 4); a2 += __shfl_xor(a2, 8);
    a3 += __shfl_xor(a3, 4); a3 += __shfl_xor(a3, 8);
    if (s == 0) {
        float inv = 1.f / fmaxf((float)cnt, 1.f);
        ushort4 w;
        w.x = f2b(a0 * inv); w.y = f2b(a1 * inv);
        w.z = f2b(a2 * inv); w.w = f2b(a3 * inv);
        *(ushort4*)(aggb + (size_t)c * CS + (size_t)node * 16 + p * 4) = w;
    }
}

// ---- layer v3 (MFMA): relu(agg@Wl + h@Wr + b) -> bf16 chunked -------------
// 16x16x32 bf16 MFMA. Weights pre-swizzled into B-fragment order in LDS
// (B[k=quad*8+j][n=lane&15], 16B contiguous per lane); A/H tiles pitch 72
// (16B-aligned rows). Wave w owns nodes w*16..w*16+15; 4 n-tiles x 4 MFMA.
// C/D layout (verified m89/m91): col=lane&15, row=quad*4+reg.
// In/out node features use the [4][N][16] chunked layout (nt == chunk).
__global__ void __launch_bounds__(256) layer_v3(
        const ushort_t* __restrict__ aggb, const ushort_t* __restrict__ rootb,
        const float* __restrict__ Wl, const float* __restrict__ Wr,
        const float* __restrict__ bias, ushort_t* outb) {
    __shared__ ushort_t sWlF[4096];
    __shared__ ushort_t sWrF[4096];
    __shared__ ushort_t sA[64 * MP];
    __shared__ ushort_t sH[64 * MP];
    __shared__ float sbias[HID];
    int tid = threadIdx.x;
    // stage weights into fragment order: idx = ((nt*2+ks)*64 + lane)*8 + j
    for (int idx = tid; idx < 4096; idx += 256) {
        int j = idx & 7;
        int ln = (idx >> 3) & 63;
        int t = idx >> 9;            // nt*2+ks
        int ks = t & 1, nt = t >> 1;
        int k = ks * 32 + (ln >> 4) * 8 + j;
        int n = nt * 16 + (ln & 15);
        sWlF[idx] = f2b(Wl[k * HID + n]);
        sWrF[idx] = f2b(Wr[k * HID + n]);
    }
    if (tid < HID) sbias[tid] = bias[tid];
    int node0 = blockIdx.x * 64;
    {   // stage 64 nodes x 64ch from chunked layout: 512 int4 chunks, 2/thread
#pragma unroll
        for (int pp = 0; pp < 2; ++pp) {
            int q = tid + 256 * pp;
            int cch = q >> 7;          // chunk
            int r = (q >> 1) & 63;     // node within tile
            int u2 = q & 1;            // 16B half of the 32B node-chunk row
            const int4* ga = (const int4*)(aggb + (size_t)cch * CS);
            const int4* gh = (const int4*)(rootb + (size_t)cch * CS);
            *(int4*)(sA + r * MP + cch * 16 + u2 * 8) = ga[(node0 + r) * 2 + u2];
            *(int4*)(sH + r * MP + cch * 16 + u2 * 8) = gh[(node0 + r) * 2 + u2];
        }
    }
    __syncthreads();

    int wave = tid >> 6, lane = tid & 63;
    int quad = lane >> 4, col = lane & 15;
    int arow = wave * 16 + col;
    bf16x8 aA0 = *(const bf16x8*)(sA + arow * MP + quad * 8);
    bf16x8 aA1 = *(const bf16x8*)(sA + arow * MP + 32 + quad * 8);
    bf16x8 aH0 = *(const bf16x8*)(sH + arow * MP + quad * 8);
    bf16x8 aH1 = *(const bf16x8*)(sH + arow * MP + 32 + quad * 8);
#pragma unroll
    for (int nt = 0; nt < 4; ++nt) {
        f32x4 acc = {0.f, 0.f, 0.f, 0.f};
        const bf16x8* bl = (const bf16x8*)(sWlF + nt * 1024);
        const bf16x8* br = (const bf16x8*)(sWrF + nt * 1024);
        acc = __builtin_amdgcn_mfma_f32_16x16x32_bf16(aA0, bl[lane], acc, 0, 0, 0);
        acc = __builtin_amdgcn_mfma_f32_16x16x32_bf16(aA1, bl[64 + lane], acc, 0, 0, 0);
        acc = __builtin_amdgcn_mfma_f32_16x16x32_bf16(aH0, br[lane], acc, 0, 0, 0);
        acc = __builtin_amdgcn_mfma_f32_16x16x32_bf16(aH1, br[64 + lane], acc, 0, 0, 0);
        float bv = sbias[nt * 16 + col];
#pragma unroll
        for (int r = 0; r < 4; ++r) {
            int n = node0 + wave * 16 + quad * 4 + r;
            if (n < N_NODES)
                outb[(size_t)nt * CS + (size_t)n * 16 + col] =
                    f2b(fmaxf(acc[r] + bv, 0.f));
        }
    }
}

// ---- head v2: out = h @ Wlin + blin, LDS-tiled, fp32 out ------------------
__global__ void __launch_bounds__(256) head_v2(
        const ushort_t* __restrict__ hb, const float* __restrict__ W,
        const float* __restrict__ bias, float* __restrict__ out) {
    __shared__ float sWo[HID * OUT_CH];
    __shared__ ushort_t sH[64 * SAP];
    __shared__ float sb[OUT_CH];
    int tid = threadIdx.x;
    {
        const float4* W4 = (const float4*)W;
        float4* sW4 = (float4*)sWo;
        for (int i = tid; i < HID * OUT_CH / 4; i += 256) sW4[i] = W4[i];
    }
    if (tid < OUT_CH) sb[tid] = bias[tid];
    int node0 = blockIdx.x * 64;
    {   // stage from chunked layout
#pragma unroll
        for (int pp = 0; pp < 2; ++pp) {
            int q = tid + 256 * pp;
            int cch = q >> 7;
            int r = (q >> 1) & 63;
            int u2 = q & 1;
            const int4* gh = (const int4*)(hb + (size_t)cch * CS);
            *(int4*)(sH + r * SAP + cch * 16 + u2 * 8) = gh[(node0 + r) * 2 + u2];
        }
    }
    __syncthreads();

    int c0 = (tid & 7) << 2;
    int n0 = (tid >> 3) << 1;
    float acc[2][4];
#pragma unroll
    for (int i = 0; i < 2; ++i)
#pragma unroll
        for (int j = 0; j < 4; ++j) acc[i][j] = sb[c0 + j];

#pragma unroll 4
    for (int kk = 0; kk < 32; ++kk) {
        float4 w0 = *(const float4*)&sWo[(2 * kk) * OUT_CH + c0];
        float4 w1 = *(const float4*)&sWo[(2 * kk + 1) * OUT_CH + c0];
        const float* w0p = (const float*)&w0;
        const float* w1p = (const float*)&w1;
#pragma unroll
        for (int i = 0; i < 2; ++i) {
            unsigned uh = *(const unsigned*)(sH + (n0 + i) * SAP + 2 * kk);
            float h0 = blo(uh), h1 = bhi(uh);
#pragma unroll
            for (int j = 0; j < 4; ++j) acc[i][j] += h0 * w0p[j] + h1 * w1p[j];
        }
    }

#pragma unroll
    for (int i = 0; i < 2; ++i) {
        int n = node0 + n0 + i;
        if (n < N_NODES) {
            float4 o4;
            o4.x = acc[i][0]; o4.y = acc[i][1]; o4.z = acc[i][2]; o4.w = acc[i][3];
            *(float4*)(out + (size_t)n * OUT_CH + c0) = o4;
        }
    }
}

extern "C" void kernel_launch(void* const* d_in, const int* in_sizes, int n_in,
                              void* d_out, int out_size, void* d_ws, size_t ws_size,
                              hipStream_t stream) {
    const float* x    = (const float*)d_in[0];
    const int*   ei   = (const int*)d_in[1];
    const float* Wl1  = (const float*)d_in[2];
    const float* Wr1  = (const float*)d_in[3];
    const float* b1   = (const float*)d_in[4];
    const float* Wl2  = (const float*)d_in[5];
    const float* Wr2  = (const float*)d_in[6];
    const float* b2   = (const float*)d_in[7];
    const float* Wl3  = (const float*)d_in[8];
    const float* Wr3  = (const float*)d_in[9];
    const float* b3   = (const float*)d_in[10];
    const float* Wlin = (const float*)d_in[11];
    const float* blin = (const float*)d_in[12];
    float* out = (float*)d_out;

    // workspace layout (4-byte units), ~33 MB; tile overreads land in slack.
    int* ip              = (int*)d_ws;
    unsigned int* offpk  = (unsigned int*)ip;           // 100096
    int* btot            = (int*)(offpk + 100096);      // 256
    int* histG           = btot + 256;                  // NB*P = 200704
    int* csr             = histG + NB * P;              // 1600000
    ushort_t* aggb       = (ushort_t*)(csr + N_EDGES);  // 4 chunks + 8192 slack
    ushort_t* featb      = aggb + 6408192;              // 4 chunks + 8192 slack
    int* bkt             = (int*)aggb;  // bucket records alias aggb (dead until gather)

    const int GATHER_BLOCKS = 4 * GB_PER_CHUNK;          // 25000 (4 chunk phases)
    const int TILE_BLOCKS   = (N_NODES + 63) / 64;       // 1563

    // CSR build: convert+hist fused, scan, place, per-bucket fill
    convhist_kernel<<<CONV_BLOCKS, 256, 0, stream>>>(x, featb, ei, histG);
    scan_kernel<<<NB, 256, 0, stream>>>(histG, btot);
    place_kernel<<<P, 256, 0, stream>>>(ei, histG, btot, bkt);
    bucket_fill_kernel<<<NB, 256, 0, stream>>>(btot, bkt, csr, offpk);

    // layer 1 (root = bf16 x in featb; in-place featb output is block-local)
    gather_kernel<<<GATHER_BLOCKS, 256, 0, stream>>>(featb, offpk, csr, aggb);
    layer_v3<<<TILE_BLOCKS, 256, 0, stream>>>(aggb, featb, Wl1, Wr1, b1, featb);

    // layer 2
    gather_kernel<<<GATHER_BLOCKS, 256, 0, stream>>>(featb, offpk, csr, aggb);
    layer_v3<<<TILE_BLOCKS, 256, 0, stream>>>(aggb, featb, Wl2, Wr2, b2, featb);

    // layer 3
    gather_kernel<<<GATHER_BLOCKS, 256, 0, stream>>>(featb, offpk, csr, aggb);
    layer_v3<<<TILE_BLOCKS, 256, 0, stream>>>(aggb, featb, Wl3, Wr3, b3, featb);

    // head
    head_v2<<<TILE_BLOCKS, 256, 0, stream>>>(featb, Wlin, blin, out);
}

// Round 2
// 367.579 us; speedup vs baseline: 1.1037x; 1.1037x over previous
//
#include <hip/hip_runtime.h>
#include <hip/hip_bf16.h>

#define N_NODES 100000
#define N_EDGES 1600000
#define HID 64
#define OUT_CH 32

// Deterministic radix partition into dst buckets. Zero global atomics
// (R5: contended global cursors serialize device-wide at ~6 ns/atomic).
// R12 lesson: don't fuse fat-LDS GEMM onto the latency-bound gather.
#define NB 196           // ceil(100000/512) buckets of 512 consecutive dst nodes
#define P 1024           // partition blocks
#define EPP ((N_EDGES + P - 1) / P)   // 1563 edges per block
#define BKCAP 10240      // LDS csr staging cap (bucket mean 8192, sigma ~90)
#define SAP 66           // bf16 tile pitch for head (conflict-free)
#define MP 72            // bf16 tile pitch for MFMA layer (16B-aligned rows)

// Channel-chunked feature layout: features stored as [4][N_NODES][16] bf16.
// Each 16-channel chunk is 3.2 MB -> fits a 4 MB per-XCD L2, so a
// chunk-phased gather reads ~100% from L2 instead of Infinity Cache.
#define CS (N_NODES * 16)        // ushorts per chunk (3.2 MB)
#define GB_PER_CHUNK 6250        // gather blocks per chunk phase (16 nodes/block)

typedef unsigned short ushort_t;
typedef short bf16x8 __attribute__((ext_vector_type(8)));
typedef float f32x4 __attribute__((ext_vector_type(4)));

// bf16 helpers (RNE)
__device__ __forceinline__ ushort_t f2b(float f) {
    union { float f; unsigned u; } un; un.f = f;
    unsigned r = un.u + 0x7FFF + ((un.u >> 16) & 1);
    return (ushort_t)(r >> 16);
}
__device__ __forceinline__ float b2f(ushort_t u) {
    union { unsigned u; float f; } un; un.u = ((unsigned)u) << 16;
    return un.f;
}
__device__ __forceinline__ float blo(unsigned u) {
    union { unsigned u; float f; } un; un.u = u << 16; return un.f;
}
__device__ __forceinline__ float bhi(unsigned u) {
    union { unsigned u; float f; } un; un.u = u & 0xFFFF0000u; return un.f;
}

__device__ __forceinline__ int get_dst(const int* __restrict__ ei, int is64, int e) {
    return is64 ? ((const int2*)ei)[N_EDGES + e].x : ei[N_EDGES + e];
}
__device__ __forceinline__ int get_src(const int* __restrict__ ei, int is64, int e) {
    return is64 ? ((const int2*)ei)[e].x : ei[e];
}

// inline edge-dtype probe: int64 => odd 32-bit words all 0 (first wave)
__device__ __forceinline__ void detect_is64(const int* __restrict__ ei,
                                            int* __restrict__ sflag, int tid) {
    if (tid < 64) {
        int v = ei[2 * tid + 1];
        unsigned long long ball = __ballot(v == 0);
        if (tid == 0) *sflag = (ball == ~0ull) ? 1 : 0;
    }
}

// ---- convert x -> bf16 CHUNKED layout + bucket histograms (blocks <P) -----
#define CONV_BLOCKS ((N_NODES * HID / 4) / 256)   // 6250
__global__ void __launch_bounds__(256) convhist_kernel(
        const float* __restrict__ x, ushort_t* __restrict__ xb,
        const int* __restrict__ ei, int* __restrict__ histG) {
    int i = blockIdx.x * 256 + threadIdx.x;
    if (i < N_NODES * HID / 4) {
        float4 v = ((const float4*)x)[i];
        ushort4 o;
        o.x = f2b(v.x); o.y = f2b(v.y); o.z = f2b(v.z); o.w = f2b(v.w);
        // i covers channels 4g..4g+3 of node i>>4; chunk c = g>>2.
        int node = i >> 4, g = i & 15, c = g >> 2, pos = g & 3;
        ((ushort4*)(xb + (size_t)c * CS))[node * 4 + pos] = o;
    }
    if (blockIdx.x >= P) return;
    __shared__ int sflag;
    __shared__ int lh[NB];
    int tid = threadIdx.x;
    detect_is64(ei, &sflag, tid);
    for (int k = tid; k < NB; k += 256) lh[k] = 0;
    __syncthreads();
    int is64 = sflag;
    int e0 = blockIdx.x * EPP;
    int e1 = min(e0 + EPP, N_EDGES);
    for (int e = e0 + tid; e < e1; e += 256) {
        int d = get_dst(ei, is64, e);
        atomicAdd(&lh[d >> 9], 1);
    }
    __syncthreads();
    for (int k = tid; k < NB; k += 256) histG[k * P + blockIdx.x] = lh[k];
}

// ---- per-bucket exclusive scan over P block-counts (4 elems/thread) -------
__global__ void __launch_bounds__(256) scan_kernel(int* __restrict__ histG,
                                                   int* __restrict__ btot) {
    __shared__ int ps[256];
    int b = blockIdx.x;
    int tid = threadIdx.x;
    int base4 = b * P + 4 * tid;
    int v0 = histG[base4], v1 = histG[base4 + 1], v2 = histG[base4 + 2], v3 = histG[base4 + 3];
    int pv = v0 + v1 + v2 + v3;
    ps[tid] = pv;
    __syncthreads();
    for (int d = 1; d < 256; d <<= 1) {
        int t = (tid >= d) ? ps[tid - d] : 0;
        __syncthreads();
        ps[tid] += t;
        __syncthreads();
    }
    int e = ps[tid] - pv;
    histG[base4] = e; e += v0;
    histG[base4 + 1] = e; e += v1;
    histG[base4 + 2] = e; e += v2;
    histG[base4 + 3] = e;
    if (tid == 255) btot[b] = ps[255];
}

// ---- place records at deterministic offsets (LDS cursors only) ------------
// Bucket bases from local 196-wide scan of btot. record = (dst&511)<<17 | src
__global__ void __launch_bounds__(256) place_kernel(
        const int* __restrict__ ei, const int* __restrict__ histG,
        const int* __restrict__ btot, int* __restrict__ bkt) {
    __shared__ int lcur[NB];
    __shared__ int ss[256];
    __shared__ int sflag;
    int tid = threadIdx.x;
    detect_is64(ei, &sflag, tid);
    int v = (tid < NB) ? btot[tid] : 0;
    ss[tid] = v;
    __syncthreads();
    for (int d = 1; d < 256; d <<= 1) {
        int t = (tid >= d) ? ss[tid - d] : 0;
        __syncthreads();
        ss[tid] += t;
        __syncthreads();
    }
    if (tid < NB) lcur[tid] = (ss[tid] - v) + histG[tid * P + blockIdx.x];
    __syncthreads();
    int is64 = sflag;
    int e0 = blockIdx.x * EPP;
    int e1 = min(e0 + EPP, N_EDGES);
    for (int e = e0 + tid; e < e1; e += 256) {
        int s = get_src(ei, is64, e);
        int d = get_dst(ei, is64, e);
        int val = ((d & 511) << 17) | s;
        int p = atomicAdd(&lcur[d >> 9], 1);
        bkt[p] = val;
    }
}

// ---- per-bucket csr build in LDS + packed off|deg -------------------------
// offpk[n] = (abs_off & 0x1FFFFF) | (deg << 21); bucket base from local scan.
__global__ void __launch_bounds__(256) bucket_fill_kernel(
        const int* __restrict__ btot, const int* __restrict__ bkt,
        int* __restrict__ csr, unsigned int* __restrict__ offpk) {
    __shared__ int lcnt[512];
    __shared__ int loff[512];
    __shared__ int lcur[512];
    __shared__ int ps[256];
    __shared__ int scsr[BKCAP];
    __shared__ int sbase;
    int b = blockIdx.x;
    int tid = threadIdx.x;
    int m = btot[b];
    int vb = (tid < NB) ? btot[tid] : 0;
    ps[tid] = vb;
    __syncthreads();
    for (int d = 1; d < 256; d <<= 1) {
        int t = (tid >= d) ? ps[tid - d] : 0;
        __syncthreads();
        ps[tid] += t;
        __syncthreads();
    }
    if (tid == b) sbase = ps[tid] - vb;   // exclusive prefix at b
    __syncthreads();
    int base = sbase;
    int n0 = b << 9;
    int nn = min(512, N_NODES - n0);

    lcnt[tid] = 0;
    lcnt[tid + 256] = 0;
    __syncthreads();
    for (int i = tid; i < m; i += 256) atomicAdd(&lcnt[bkt[base + i] >> 17], 1);
    __syncthreads();
    int a0 = lcnt[2 * tid], a1 = lcnt[2 * tid + 1];
    int pv = a0 + a1;
    ps[tid] = pv;
    __syncthreads();
    for (int d = 1; d < 256; d <<= 1) {
        int t = (tid >= d) ? ps[tid - d] : 0;
        __syncthreads();
        ps[tid] += t;
        __syncthreads();
    }
    int excl = ps[tid] - pv;
    loff[2 * tid] = excl;
    loff[2 * tid + 1] = excl + a0;
    lcur[2 * tid] = excl;
    lcur[2 * tid + 1] = excl + a0;
    __syncthreads();
    bool fit = (m <= BKCAP);
    for (int i = tid; i < m; i += 256) {
        int val = bkt[base + i];
        int dl = val >> 17;
        int p = atomicAdd(&lcur[dl], 1);
        if (fit) scsr[p] = val & 0x1FFFF;
        else csr[base + p] = val & 0x1FFFF;
    }
    __syncthreads();
    if (fit)
        for (int i = tid; i < m; i += 256) csr[base + i] = scsr[i];
    for (int i = tid; i < nn; i += 256)
        offpk[n0 + i] = (unsigned int)((base + loff[i]) | (lcnt[i] << 21));
}

// ---- gather: chunk-phased, L2-resident, shfl-distributed csr --------------
// Phase c (blocks [c*6250, (c+1)*6250)) reads ONLY chunk c (3.2 MB ->
// per-XCD L2 resident; dispatch order paces phases). Per wave: 4 nodes
// (16 lanes each: s = edge slot 0..3, p = channel-quad 0..3). Per
// 16-edge iteration: ONE guarded csr load per lane (16 edges covered by
// the node's 16 lanes), shfl-broadcast to the consuming lanes, predicated
// int2 feature loads. 32-bit feature indexing (chunk is 3.2 MB). No
// nontemporal: csr + chunk stay cached.
__global__ void __launch_bounds__(256) gather_kernel(
        const ushort_t* __restrict__ hb, const unsigned int* __restrict__ offpk,
        const int* __restrict__ csr, ushort_t* __restrict__ aggb) {
    int bid = blockIdx.x;
    int c = bid / GB_PER_CHUNK;
    int nb = bid - c * GB_PER_CHUNK;
    int tid = threadIdx.x;
    int o = tid & 63;
    int node = nb * 16 + (tid >> 6) * 4 + (o >> 4);   // 6250*16 = 100000 exact
    int s = (o >> 2) & 3;      // edge slot within node
    int p = o & 3;             // channel-quad (int2 position) within chunk row
    unsigned int v = offpk[node];
    int off = (int)(v & 0x1FFFFFu);
    int cnt = (int)(v >> 21);
    const int2* fc2 = (const int2*)(hb + (size_t)c * CS);
    float a0 = 0.f, a1 = 0.f, a2 = 0.f, a3 = 0.f;
    int m = (cnt + 15) >> 4;
    m = max(m, __shfl_xor(m, 16));
    m = max(m, __shfl_xor(m, 32));   // max iters over the wave's 4 nodes
    int ol = o & 15;
    int gb = o & 48;
    for (int t = 0; t < m; ++t) {
        int ebase = t * 16;
        int el = ebase + ol;
        int idxv = (el < cnt) ? csr[off + el] : 0;
#pragma unroll
        for (int j = 0; j < 4; ++j) {
            int e = ebase + j * 4 + s;
            int idx = __shfl(idxv, gb + j * 4 + s);
            if (e < cnt) {
                int2 u = fc2[idx * 4 + p];
                a0 += blo(u.x); a1 += bhi(u.x);
                a2 += blo(u.y); a3 += bhi(u.y);
            }
        }
    }
    // reduce over edge slot s (lane bits 2..3); stays within the 16-lane group
    a0 += __shfl_xor(a0, 4); a0 += __shfl_xor(a0, 8);
    a1 += __shfl_xor(a1, 4); a1 += __shfl_xor(a1, 8);
    a2 += __shfl_xor(a2, 4); a2 += __shfl_xor(a2, 8);
    a3 += __shfl_xor(a3, 4); a3 += __shfl_xor(a3, 8);
    if (s == 0) {
        float inv = 1.f / fmaxf((float)cnt, 1.f);
        ushort4 w;
        w.x = f2b(a0 * inv); w.y = f2b(a1 * inv);
        w.z = f2b(a2 * inv); w.w = f2b(a3 * inv);
        *(ushort4*)(aggb + (size_t)c * CS + (size_t)node * 16 + p * 4) = w;
    }
}

// ---- layer v3 (MFMA): relu(agg@Wl + h@Wr + b) -> bf16 chunked -------------
// 16x16x32 bf16 MFMA. Weights pre-swizzled into B-fragment order in LDS
// (B[k=quad*8+j][n=lane&15], 16B contiguous per lane); A/H tiles pitch 72
// (16B-aligned rows). Wave w owns nodes w*16..w*16+15; 4 n-tiles x 4 MFMA.
// C/D layout (verified m89/m91): col=lane&15, row=quad*4+reg.
// In/out node features use the [4][N][16] chunked layout (nt == chunk).
__global__ void __launch_bounds__(256) layer_v3(
        const ushort_t* __restrict__ aggb, const ushort_t* __restrict__ rootb,
        const float* __restrict__ Wl, const float* __restrict__ Wr,
        const float* __restrict__ bias, ushort_t* outb) {
    __shared__ ushort_t sWlF[4096];
    __shared__ ushort_t sWrF[4096];
    __shared__ ushort_t sA[64 * MP];
    __shared__ ushort_t sH[64 * MP];
    __shared__ float sbias[HID];
    int tid = threadIdx.x;
    // stage weights into fragment order: idx = ((nt*2+ks)*64 + lane)*8 + j
    for (int idx = tid; idx < 4096; idx += 256) {
        int j = idx & 7;
        int ln = (idx >> 3) & 63;
        int t = idx >> 9;            // nt*2+ks
        int ks = t & 1, nt = t >> 1;
        int k = ks * 32 + (ln >> 4) * 8 + j;
        int n = nt * 16 + (ln & 15);
        sWlF[idx] = f2b(Wl[k * HID + n]);
        sWrF[idx] = f2b(Wr[k * HID + n]);
    }
    if (tid < HID) sbias[tid] = bias[tid];
    int node0 = blockIdx.x * 64;
    {   // stage 64 nodes x 64ch from chunked layout: 512 int4 chunks, 2/thread
#pragma unroll
        for (int pp = 0; pp < 2; ++pp) {
            int q = tid + 256 * pp;
            int cch = q >> 7;          // chunk
            int r = (q >> 1) & 63;     // node within tile
            int u2 = q & 1;            // 16B half of the 32B node-chunk row
            const int4* ga = (const int4*)(aggb + (size_t)cch * CS);
            const int4* gh = (const int4*)(rootb + (size_t)cch * CS);
            *(int4*)(sA + r * MP + cch * 16 + u2 * 8) = ga[(node0 + r) * 2 + u2];
            *(int4*)(sH + r * MP + cch * 16 + u2 * 8) = gh[(node0 + r) * 2 + u2];
        }
    }
    __syncthreads();

    int wave = tid >> 6, lane = tid & 63;
    int quad = lane >> 4, col = lane & 15;
    int arow = wave * 16 + col;
    bf16x8 aA0 = *(const bf16x8*)(sA + arow * MP + quad * 8);
    bf16x8 aA1 = *(const bf16x8*)(sA + arow * MP + 32 + quad * 8);
    bf16x8 aH0 = *(const bf16x8*)(sH + arow * MP + quad * 8);
    bf16x8 aH1 = *(const bf16x8*)(sH + arow * MP + 32 + quad * 8);
#pragma unroll
    for (int nt = 0; nt < 4; ++nt) {
        f32x4 acc = {0.f, 0.f, 0.f, 0.f};
        const bf16x8* bl = (const bf16x8*)(sWlF + nt * 1024);
        const bf16x8* br = (const bf16x8*)(sWrF + nt * 1024);
        acc = __builtin_amdgcn_mfma_f32_16x16x32_bf16(aA0, bl[lane], acc, 0, 0, 0);
        acc = __builtin_amdgcn_mfma_f32_16x16x32_bf16(aA1, bl[64 + lane], acc, 0, 0, 0);
        acc = __builtin_amdgcn_mfma_f32_16x16x32_bf16(aH0, br[lane], acc, 0, 0, 0);
        acc = __builtin_amdgcn_mfma_f32_16x16x32_bf16(aH1, br[64 + lane], acc, 0, 0, 0);
        float bv = sbias[nt * 16 + col];
#pragma unroll
        for (int r = 0; r < 4; ++r) {
            int n = node0 + wave * 16 + quad * 4 + r;
            if (n < N_NODES)
                outb[(size_t)nt * CS + (size_t)n * 16 + col] =
                    f2b(fmaxf(acc[r] + bv, 0.f));
        }
    }
}

// ---- head v2: out = h @ Wlin + blin, LDS-tiled, fp32 out ------------------
__global__ void __launch_bounds__(256) head_v2(
        const ushort_t* __restrict__ hb, const float* __restrict__ W,
        const float* __restrict__ bias, float* __restrict__ out) {
    __shared__ float sWo[HID * OUT_CH];
    __shared__ ushort_t sH[64 * SAP];
    __shared__ float sb[OUT_CH];
    int tid = threadIdx.x;
    {
        const float4* W4 = (const float4*)W;
        float4* sW4 = (float4*)sWo;
        for (int i = tid; i < HID * OUT_CH / 4; i += 256) sW4[i] = W4[i];
    }
    if (tid < OUT_CH) sb[tid] = bias[tid];
    int node0 = blockIdx.x * 64;
    {   // stage from chunked layout
#pragma unroll
        for (int pp = 0; pp < 2; ++pp) {
            int q = tid + 256 * pp;
            int cch = q >> 7;
            int r = (q >> 1) & 63;
            int u2 = q & 1;
            const int4* gh = (const int4*)(hb + (size_t)cch * CS);
            *(int4*)(sH + r * SAP + cch * 16 + u2 * 8) = gh[(node0 + r) * 2 + u2];
        }
    }
    __syncthreads();

    int c0 = (tid & 7) << 2;
    int n0 = (tid >> 3) << 1;
    float acc[2][4];
#pragma unroll
    for (int i = 0; i < 2; ++i)
#pragma unroll
        for (int j = 0; j < 4; ++j) acc[i][j] = sb[c0 + j];

#pragma unroll 4
    for (int kk = 0; kk < 32; ++kk) {
        float4 w0 = *(const float4*)&sWo[(2 * kk) * OUT_CH + c0];
        float4 w1 = *(const float4*)&sWo[(2 * kk + 1) * OUT_CH + c0];
        const float* w0p = (const float*)&w0;
        const float* w1p = (const float*)&w1;
#pragma unroll
        for (int i = 0; i < 2; ++i) {
            unsigned uh = *(const unsigned*)(sH + (n0 + i) * SAP + 2 * kk);
            float h0 = blo(uh), h1 = bhi(uh);
#pragma unroll
            for (int j = 0; j < 4; ++j) acc[i][j] += h0 * w0p[j] + h1 * w1p[j];
        }
    }

#pragma unroll
    for (int i = 0; i < 2; ++i) {
        int n = node0 + n0 + i;
        if (n < N_NODES) {
            float4 o4;
            o4.x = acc[i][0]; o4.y = acc[i][1]; o4.z = acc[i][2]; o4.w = acc[i][3];
            *(float4*)(out + (size_t)n * OUT_CH + c0) = o4;
        }
    }
}

extern "C" void kernel_launch(void* const* d_in, const int* in_sizes, int n_in,
                              void* d_out, int out_size, void* d_ws, size_t ws_size,
                              hipStream_t stream) {
    const float* x    = (const float*)d_in[0];
    const int*   ei   = (const int*)d_in[1];
    const float* Wl1  = (const float*)d_in[2];
    const float* Wr1  = (const float*)d_in[3];
    const float* b1   = (const float*)d_in[4];
    const float* Wl2  = (const float*)d_in[5];
    const float* Wr2  = (const float*)d_in[6];
    const float* b2   = (const float*)d_in[7];
    const float* Wl3  = (const float*)d_in[8];
    const float* Wr3  = (const float*)d_in[9];
    const float* b3   = (const float*)d_in[10];
    const float* Wlin = (const float*)d_in[11];
    const float* blin = (const float*)d_in[12];
    float* out = (float*)d_out;

    // workspace layout (4-byte units), ~33 MB; tile overreads land in slack.
    int* ip              = (int*)d_ws;
    unsigned int* offpk  = (unsigned int*)ip;           // 100096
    int* btot            = (int*)(offpk + 100096);      // 256
    int* histG           = btot + 256;                  // NB*P = 200704
    int* csr             = histG + NB * P;              // 1600000
    ushort_t* aggb       = (ushort_t*)(csr + N_EDGES);  // 4 chunks + 8192 slack
    ushort_t* featb      = aggb + 6408192;              // 4 chunks + 8192 slack
    int* bkt             = (int*)aggb;  // bucket records alias aggb (dead until gather)

    const int GATHER_BLOCKS = 4 * GB_PER_CHUNK;          // 25000 (4 chunk phases)
    const int TILE_BLOCKS   = (N_NODES + 63) / 64;       // 1563

    // CSR build: convert+hist fused, scan, place, per-bucket fill
    convhist_kernel<<<CONV_BLOCKS, 256, 0, stream>>>(x, featb, ei, histG);
    scan_kernel<<<NB, 256, 0, stream>>>(histG, btot);
    place_kernel<<<P, 256, 0, stream>>>(ei, histG, btot, bkt);
    bucket_fill_kernel<<<NB, 256, 0, stream>>>(btot, bkt, csr, offpk);

    // layer 1 (root = bf16 x in featb; in-place featb output is block-local)
    gather_kernel<<<GATHER_BLOCKS, 256, 0, stream>>>(featb, offpk, csr, aggb);
    layer_v3<<<TILE_BLOCKS, 256, 0, stream>>>(aggb, featb, Wl1, Wr1, b1, featb);

    // layer 2
    gather_kernel<<<GATHER_BLOCKS, 256, 0, stream>>>(featb, offpk, csr, aggb);
    layer_v3<<<TILE_BLOCKS, 256, 0, stream>>>(aggb, featb, Wl2, Wr2, b2, featb);

    // layer 3
    gather_kernel<<<GATHER_BLOCKS, 256, 0, stream>>>(featb, offpk, csr, aggb);
    layer_v3<<<TILE_BLOCKS, 256, 0, stream>>>(aggb, featb, Wl3, Wr3, b3, featb);

    // head
    head_v2<<<TILE_BLOCKS, 256, 0, stream>>>(featb, Wlin, blin, out);
}

// Round 3
// 302.607 us; speedup vs baseline: 1.3406x; 1.2147x over previous
//
#include <hip/hip_runtime.h>
#include <hip/hip_bf16.h>

#define N_NODES 100000
#define N_EDGES 1600000
#define HID 64
#define OUT_CH 32

// Deterministic radix partition into dst buckets. Zero global atomics
// (R5: contended global cursors serialize device-wide at ~6 ns/atomic).
// R12 lesson: don't fuse fat-LDS GEMM onto the latency-bound gather.
// R1/R2 lesson: channel-chunked L2-resident gather LOSES to monolithic
// (request-rate bound: chunking doubles request count, quadruples csr reads).
#define NB 196           // ceil(100000/512) buckets of 512 consecutive dst nodes
#define P 1024           // partition blocks
#define EPP ((N_EDGES + P - 1) / P)   // 1563 edges per block
#define BKCAP 10240      // LDS csr staging cap (bucket mean 8192, sigma ~90)
#define SAP 66           // bf16 tile pitch for head (conflict-free)
#define MP 72            // bf16 tile pitch for MFMA layer (16B-aligned rows)

typedef unsigned short ushort_t;
typedef short bf16x8 __attribute__((ext_vector_type(8)));
typedef float f32x4 __attribute__((ext_vector_type(4)));

// bf16 helpers (RNE)
__device__ __forceinline__ ushort_t f2b(float f) {
    union { float f; unsigned u; } un; un.f = f;
    unsigned r = un.u + 0x7FFF + ((un.u >> 16) & 1);
    return (ushort_t)(r >> 16);
}
__device__ __forceinline__ float b2f(ushort_t u) {
    union { unsigned u; float f; } un; un.u = ((unsigned)u) << 16;
    return un.f;
}
__device__ __forceinline__ float blo(unsigned u) {
    union { unsigned u; float f; } un; un.u = u << 16; return un.f;
}
__device__ __forceinline__ float bhi(unsigned u) {
    union { unsigned u; float f; } un; un.u = u & 0xFFFF0000u; return un.f;
}

__device__ __forceinline__ int get_dst(const int* __restrict__ ei, int is64, int e) {
    return is64 ? ((const int2*)ei)[N_EDGES + e].x : ei[N_EDGES + e];
}
__device__ __forceinline__ int get_src(const int* __restrict__ ei, int is64, int e) {
    return is64 ? ((const int2*)ei)[e].x : ei[e];
}

// inline edge-dtype probe: int64 => odd 32-bit words all 0 (first wave)
__device__ __forceinline__ void detect_is64(const int* __restrict__ ei,
                                            int* __restrict__ sflag, int tid) {
    if (tid < 64) {
        int v = ei[2 * tid + 1];
        unsigned long long ball = __ballot(v == 0);
        if (tid == 0) *sflag = (ball == ~0ull) ? 1 : 0;
    }
}

// ---- weight prep: swizzle 6 matrices into MFMA B-fragment order, bf16 ----
// Done ONCE (6 blocks) instead of per-tile-block scattered scalar loads
// (was 8192 scattered 4B loads/block x 1563 blocks x 3 layers = 38M L2
// requests — more than all gathers combined). Fragment order:
// idx = ((nt*2+ks)*64 + lane)*8 + j  <-  W[k*HID+n], k=ks*32+(lane>>4)*8+j,
// n = nt*16 + (lane&15).
__global__ void __launch_bounds__(256) wprep_kernel(
        const float* __restrict__ W0, const float* __restrict__ W1,
        const float* __restrict__ W2, const float* __restrict__ W3,
        const float* __restrict__ W4, const float* __restrict__ W5,
        ushort_t* __restrict__ wpk) {
    const float* Ws[6] = {W0, W1, W2, W3, W4, W5};
    const float* W = Ws[blockIdx.x];
    ushort_t* d = wpk + blockIdx.x * 4096;
    for (int idx = threadIdx.x; idx < 4096; idx += 256) {
        int j = idx & 7;
        int ln = (idx >> 3) & 63;
        int t = idx >> 9;            // nt*2+ks
        int ks = t & 1, nt = t >> 1;
        int k = ks * 32 + (ln >> 4) * 8 + j;
        int n = nt * 16 + (ln & 15);
        d[idx] = f2b(W[k * HID + n]);
    }
}

// ---- convert x -> bf16 (all 6250 blocks) + bucket histograms (blocks <P) --
#define CONV_BLOCKS ((N_NODES * HID / 4) / 256)   // 6250
__global__ void __launch_bounds__(256) convhist_kernel(
        const float* __restrict__ x, ushort_t* __restrict__ xb,
        const int* __restrict__ ei, int* __restrict__ histG) {
    int i = blockIdx.x * 256 + threadIdx.x;
    if (i < N_NODES * HID / 4) {
        float4 v = ((const float4*)x)[i];
        ushort4 o;
        o.x = f2b(v.x); o.y = f2b(v.y); o.z = f2b(v.z); o.w = f2b(v.w);
        ((ushort4*)xb)[i] = o;
    }
    if (blockIdx.x >= P) return;
    __shared__ int sflag;
    __shared__ int lh[NB];
    int tid = threadIdx.x;
    detect_is64(ei, &sflag, tid);
    for (int k = tid; k < NB; k += 256) lh[k] = 0;
    __syncthreads();
    int is64 = sflag;
    int e0 = blockIdx.x * EPP;
    int e1 = min(e0 + EPP, N_EDGES);
    for (int e = e0 + tid; e < e1; e += 256) {
        int d = get_dst(ei, is64, e);
        atomicAdd(&lh[d >> 9], 1);
    }
    __syncthreads();
    for (int k = tid; k < NB; k += 256) histG[k * P + blockIdx.x] = lh[k];
}

// ---- per-bucket exclusive scan over P block-counts (4 elems/thread) -------
__global__ void __launch_bounds__(256) scan_kernel(int* __restrict__ histG,
                                                   int* __restrict__ btot) {
    __shared__ int ps[256];
    int b = blockIdx.x;
    int tid = threadIdx.x;
    int base4 = b * P + 4 * tid;
    int v0 = histG[base4], v1 = histG[base4 + 1], v2 = histG[base4 + 2], v3 = histG[base4 + 3];
    int pv = v0 + v1 + v2 + v3;
    ps[tid] = pv;
    __syncthreads();
    for (int d = 1; d < 256; d <<= 1) {
        int t = (tid >= d) ? ps[tid - d] : 0;
        __syncthreads();
        ps[tid] += t;
        __syncthreads();
    }
    int e = ps[tid] - pv;
    histG[base4] = e; e += v0;
    histG[base4 + 1] = e; e += v1;
    histG[base4 + 2] = e; e += v2;
    histG[base4 + 3] = e;
    if (tid == 255) btot[b] = ps[255];
}

// ---- place records at deterministic offsets (LDS cursors only) ------------
// Bucket bases from local 196-wide scan of btot. record = (dst&511)<<17 | src
__global__ void __launch_bounds__(256) place_kernel(
        const int* __restrict__ ei, const int* __restrict__ histG,
        const int* __restrict__ btot, int* __restrict__ bkt) {
    __shared__ int lcur[NB];
    __shared__ int ss[256];
    __shared__ int sflag;
    int tid = threadIdx.x;
    detect_is64(ei, &sflag, tid);
    int v = (tid < NB) ? btot[tid] : 0;
    ss[tid] = v;
    __syncthreads();
    for (int d = 1; d < 256; d <<= 1) {
        int t = (tid >= d) ? ss[tid - d] : 0;
        __syncthreads();
        ss[tid] += t;
        __syncthreads();
    }
    if (tid < NB) lcur[tid] = (ss[tid] - v) + histG[tid * P + blockIdx.x];
    __syncthreads();
    int is64 = sflag;
    int e0 = blockIdx.x * EPP;
    int e1 = min(e0 + EPP, N_EDGES);
    for (int e = e0 + tid; e < e1; e += 256) {
        int s = get_src(ei, is64, e);
        int d = get_dst(ei, is64, e);
        int val = ((d & 511) << 17) | s;
        int p = atomicAdd(&lcur[d >> 9], 1);
        bkt[p] = val;
    }
}

// ---- per-bucket csr build in LDS + packed off|deg -------------------------
// offpk[n] = (abs_off & 0x1FFFFF) | (deg << 21); bucket base from local scan.
__global__ void __launch_bounds__(256) bucket_fill_kernel(
        const int* __restrict__ btot, const int* __restrict__ bkt,
        int* __restrict__ csr, unsigned int* __restrict__ offpk) {
    __shared__ int lcnt[512];
    __shared__ int loff[512];
    __shared__ int lcur[512];
    __shared__ int ps[256];
    __shared__ int scsr[BKCAP];
    __shared__ int sbase;
    int b = blockIdx.x;
    int tid = threadIdx.x;
    int m = btot[b];
    int vb = (tid < NB) ? btot[tid] : 0;
    ps[tid] = vb;
    __syncthreads();
    for (int d = 1; d < 256; d <<= 1) {
        int t = (tid >= d) ? ps[tid - d] : 0;
        __syncthreads();
        ps[tid] += t;
        __syncthreads();
    }
    if (tid == b) sbase = ps[tid] - vb;   // exclusive prefix at b
    __syncthreads();
    int base = sbase;
    int n0 = b << 9;
    int nn = min(512, N_NODES - n0);

    lcnt[tid] = 0;
    lcnt[tid + 256] = 0;
    __syncthreads();
    for (int i = tid; i < m; i += 256) atomicAdd(&lcnt[bkt[base + i] >> 17], 1);
    __syncthreads();
    int a0 = lcnt[2 * tid], a1 = lcnt[2 * tid + 1];
    int pv = a0 + a1;
    ps[tid] = pv;
    __syncthreads();
    for (int d = 1; d < 256; d <<= 1) {
        int t = (tid >= d) ? ps[tid - d] : 0;
        __syncthreads();
        ps[tid] += t;
        __syncthreads();
    }
    int excl = ps[tid] - pv;
    loff[2 * tid] = excl;
    loff[2 * tid + 1] = excl + a0;
    lcur[2 * tid] = excl;
    lcur[2 * tid + 1] = excl + a0;
    __syncthreads();
    bool fit = (m <= BKCAP);
    for (int i = tid; i < m; i += 256) {
        int val = bkt[base + i];
        int dl = val >> 17;
        int p = atomicAdd(&lcur[dl], 1);
        if (fit) scsr[p] = val & 0x1FFFF;
        else csr[base + p] = val & 0x1FFFF;
    }
    __syncthreads();
    if (fit)
        for (int i = tid; i < m; i += 256) csr[base + i] = scsr[i];
    for (int i = tid; i < nn; i += 256)
        offpk[n0 + i] = (unsigned int)((base + loff[i]) | (lcnt[i] << 21));
}

// ---- gather: 4 edges per wave-iter, 16-deep unroll (4 int2 loads/lane) ----
__global__ void __launch_bounds__(256) gather_kernel(
        const ushort_t* __restrict__ hb, const unsigned int* __restrict__ offpk,
        const int* __restrict__ csr, ushort_t* __restrict__ aggb) {
    int node = blockIdx.x * 4 + (threadIdx.x >> 6);
    if (node >= N_NODES) return;
    int o = threadIdx.x & 63;
    int q4 = o >> 4;          // quarter 0..3 = edge slot
    int l = o & 15;           // channel group 4l..4l+3
    unsigned int v = offpk[node];
    int off0 = (int)(v & 0x1FFFFFu);
    int cnt = (int)(v >> 21);
    float a0 = 0.f, a1 = 0.f, a2 = 0.f, a3 = 0.f;
    int base = off0;
    int rem = cnt;
    while (rem > 0) {
        int take = min(rem, 64);
        int idxv = (o < take) ? csr[base + o] : 0;
        int j = 0;
        for (; j + 16 <= take; j += 16) {
            int i0 = __shfl(idxv, j + q4);
            int i1 = __shfl(idxv, j + 4 + q4);
            int i2 = __shfl(idxv, j + 8 + q4);
            int i3 = __shfl(idxv, j + 12 + q4);
            int2 u0 = ((const int2*)(hb + (size_t)i0 * HID))[l];
            int2 u1 = ((const int2*)(hb + (size_t)i1 * HID))[l];
            int2 u2 = ((const int2*)(hb + (size_t)i2 * HID))[l];
            int2 u3 = ((const int2*)(hb + (size_t)i3 * HID))[l];
            a0 += (blo(u0.x) + blo(u1.x)) + (blo(u2.x) + blo(u3.x));
            a1 += (bhi(u0.x) + bhi(u1.x)) + (bhi(u2.x) + bhi(u3.x));
            a2 += (blo(u0.y) + blo(u1.y)) + (blo(u2.y) + blo(u3.y));
            a3 += (bhi(u0.y) + bhi(u1.y)) + (bhi(u2.y) + bhi(u3.y));
        }
        for (; j < take; j += 4) {
            int e = j + q4;
            bool valid = (e < take);
            int idx = __shfl(idxv, valid ? e : 0);
            if (valid) {
                int2 u = ((const int2*)(hb + (size_t)idx * HID))[l];
                a0 += blo(u.x); a1 += bhi(u.x);
                a2 += blo(u.y); a3 += bhi(u.y);
            }
        }
        base += take;
        rem -= take;
    }
    a0 += __shfl_xor(a0, 16); a0 += __shfl_xor(a0, 32);
    a1 += __shfl_xor(a1, 16); a1 += __shfl_xor(a1, 32);
    a2 += __shfl_xor(a2, 16); a2 += __shfl_xor(a2, 32);
    a3 += __shfl_xor(a3, 16); a3 += __shfl_xor(a3, 32);
    if (o < 16) {
        float inv = 1.f / fmaxf((float)cnt, 1.f);
        ushort4 w;
        w.x = f2b(a0 * inv); w.y = f2b(a1 * inv);
        w.z = f2b(a2 * inv); w.w = f2b(a3 * inv);
        *(ushort4*)(aggb + (size_t)node * HID + l * 4) = w;
    }
}

// ---- layer v4 (MFMA): relu(agg@Wl + h@Wr + b) -> bf16 ---------------------
// 16x16x32 bf16 MFMA. Weights arrive PRE-SWIZZLED (wprep_kernel) in fragment
// order: contiguous int4 copy into LDS (4 coalesced int4/thread vs 8192
// scattered scalar loads). A/H tiles pitch 72 (16B-aligned rows). Wave w
// owns nodes w*16..w*16+15; 4 n-tiles x 4 MFMA.
// C/D layout (verified m89/m91): col=lane&15, row=quad*4+reg.
__global__ void __launch_bounds__(256) layer_v4(
        const ushort_t* __restrict__ aggb, const ushort_t* __restrict__ rootb,
        const ushort_t* __restrict__ wpk, const float* __restrict__ bias,
        ushort_t* outb) {
    __shared__ __align__(16) ushort_t sWlF[4096];
    __shared__ __align__(16) ushort_t sWrF[4096];
    __shared__ __align__(16) ushort_t sA[64 * MP];
    __shared__ __align__(16) ushort_t sH[64 * MP];
    __shared__ float sbias[HID];
    int tid = threadIdx.x;
    {   // weights: pre-swizzled bf16, contiguous coalesced int4 copy
        const int4* w4 = (const int4*)wpk;     // Wl: 512 int4, Wr: 512 int4
        int4* sl4 = (int4*)sWlF;
        int4* sr4 = (int4*)sWrF;
#pragma unroll
        for (int p = 0; p < 2; ++p) {
            int i = tid + 256 * p;
            sl4[i] = w4[i];
            sr4[i] = w4[512 + i];
        }
    }
    if (tid < HID) sbias[tid] = bias[tid];
    size_t tbase = (size_t)blockIdx.x * 64 * HID;
    {   // 512 int4 chunks, 2 per thread (overread lands in slack)
        const int4* ga = (const int4*)(aggb + tbase);
        const int4* gh = (const int4*)(rootb + tbase);
#pragma unroll
        for (int p = 0; p < 2; ++p) {
            int q = tid + 256 * p;
            int r = q >> 3, u = q & 7;
            *(int4*)(sA + r * MP + u * 8) = ga[q];
            *(int4*)(sH + r * MP + u * 8) = gh[q];
        }
    }
    __syncthreads();

    int wave = tid >> 6, lane = tid & 63;
    int quad = lane >> 4, col = lane & 15;
    int arow = wave * 16 + col;
    bf16x8 aA0 = *(const bf16x8*)(sA + arow * MP + quad * 8);
    bf16x8 aA1 = *(const bf16x8*)(sA + arow * MP + 32 + quad * 8);
    bf16x8 aH0 = *(const bf16x8*)(sH + arow * MP + quad * 8);
    bf16x8 aH1 = *(const bf16x8*)(sH + arow * MP + 32 + quad * 8);
    int node0 = blockIdx.x * 64;
#pragma unroll
    for (int nt = 0; nt < 4; ++nt) {
        f32x4 acc = {0.f, 0.f, 0.f, 0.f};
        const bf16x8* bl = (const bf16x8*)(sWlF + nt * 1024);
        const bf16x8* br = (const bf16x8*)(sWrF + nt * 1024);
        acc = __builtin_amdgcn_mfma_f32_16x16x32_bf16(aA0, bl[lane], acc, 0, 0, 0);
        acc = __builtin_amdgcn_mfma_f32_16x16x32_bf16(aA1, bl[64 + lane], acc, 0, 0, 0);
        acc = __builtin_amdgcn_mfma_f32_16x16x32_bf16(aH0, br[lane], acc, 0, 0, 0);
        acc = __builtin_amdgcn_mfma_f32_16x16x32_bf16(aH1, br[64 + lane], acc, 0, 0, 0);
        float bv = sbias[nt * 16 + col];
#pragma unroll
        for (int r = 0; r < 4; ++r) {
            int n = node0 + wave * 16 + quad * 4 + r;
            if (n < N_NODES)
                outb[(size_t)n * HID + nt * 16 + col] = f2b(fmaxf(acc[r] + bv, 0.f));
        }
    }
}

// ---- head v2: out = h @ Wlin + blin, LDS-tiled, fp32 out ------------------
__global__ void __launch_bounds__(256) head_v2(
        const ushort_t* __restrict__ hb, const float* __restrict__ W,
        const float* __restrict__ bias, float* __restrict__ out) {
    __shared__ float sWo[HID * OUT_CH];
    __shared__ __align__(16) ushort_t sH[64 * SAP];
    __shared__ float sb[OUT_CH];
    int tid = threadIdx.x;
    {
        const float4* W4 = (const float4*)W;
        float4* sW4 = (float4*)sWo;
        for (int i = tid; i < HID * OUT_CH / 4; i += 256) sW4[i] = W4[i];
    }
    if (tid < OUT_CH) sb[tid] = bias[tid];
    size_t tbase = (size_t)blockIdx.x * 64 * HID;
    {
        const int4* gh = (const int4*)(hb + tbase);
#pragma unroll
        for (int p = 0; p < 2; ++p) {
            int q = tid + 256 * p;
            int r = q >> 3, u = q & 7;
            *(int4*)(sH + r * SAP + u * 8) = gh[q];
        }
    }
    __syncthreads();

    int c0 = (tid & 7) << 2;
    int n0 = (tid >> 3) << 1;
    float acc[2][4];
#pragma unroll
    for (int i = 0; i < 2; ++i)
#pragma unroll
        for (int j = 0; j < 4; ++j) acc[i][j] = sb[c0 + j];

#pragma unroll 4
    for (int kk = 0; kk < 32; ++kk) {
        float4 w0 = *(const float4*)&sWo[(2 * kk) * OUT_CH + c0];
        float4 w1 = *(const float4*)&sWo[(2 * kk + 1) * OUT_CH + c0];
        const float* w0p = (const float*)&w0;
        const float* w1p = (const float*)&w1;
#pragma unroll
        for (int i = 0; i < 2; ++i) {
            unsigned uh = *(const unsigned*)(sH + (n0 + i) * SAP + 2 * kk);
            float h0 = blo(uh), h1 = bhi(uh);
#pragma unroll
            for (int j = 0; j < 4; ++j) acc[i][j] += h0 * w0p[j] + h1 * w1p[j];
        }
    }

    int node0 = blockIdx.x * 64;
#pragma unroll
    for (int i = 0; i < 2; ++i) {
        int n = node0 + n0 + i;
        if (n < N_NODES) {
            float4 o4;
            o4.x = acc[i][0]; o4.y = acc[i][1]; o4.z = acc[i][2]; o4.w = acc[i][3];
            *(float4*)(out + (size_t)n * OUT_CH + c0) = o4;
        }
    }
}

extern "C" void kernel_launch(void* const* d_in, const int* in_sizes, int n_in,
                              void* d_out, int out_size, void* d_ws, size_t ws_size,
                              hipStream_t stream) {
    const float* x    = (const float*)d_in[0];
    const int*   ei   = (const int*)d_in[1];
    const float* Wl1  = (const float*)d_in[2];
    const float* Wr1  = (const float*)d_in[3];
    const float* b1   = (const float*)d_in[4];
    const float* Wl2  = (const float*)d_in[5];
    const float* Wr2  = (const float*)d_in[6];
    const float* b2   = (const float*)d_in[7];
    const float* Wl3  = (const float*)d_in[8];
    const float* Wr3  = (const float*)d_in[9];
    const float* b3   = (const float*)d_in[10];
    const float* Wlin = (const float*)d_in[11];
    const float* blin = (const float*)d_in[12];
    float* out = (float*)d_out;

    // workspace layout (4-byte units), ~33 MB; tile overreads land in slack.
    int* ip              = (int*)d_ws;
    unsigned int* offpk  = (unsigned int*)ip;           // 100096
    int* btot            = (int*)(offpk + 100096);      // 256
    int* histG           = btot + 256;                  // NB*P = 200704
    int* csr             = histG + NB * P;              // 1600000
    ushort_t* aggb       = (ushort_t*)(csr + N_EDGES);  // 6.4M bf16 + 8192 slack
    ushort_t* featb      = aggb + 6408192;              // 6.4M bf16 + 8192 slack
    ushort_t* wpk        = featb + 6408192;             // 6*4096 pre-swizzled weights
    int* bkt             = (int*)aggb;  // bucket records alias aggb (dead until gather)

    const int GATHER_BLOCKS = (N_NODES + 3) / 4;         // 25000
    const int TILE_BLOCKS   = (N_NODES + 63) / 64;       // 1563

    // weight pre-swizzle (once) + CSR build: convert+hist fused, scan,
    // place, per-bucket fill
    wprep_kernel<<<6, 256, 0, stream>>>(Wl1, Wr1, Wl2, Wr2, Wl3, Wr3, wpk);
    convhist_kernel<<<CONV_BLOCKS, 256, 0, stream>>>(x, featb, ei, histG);
    scan_kernel<<<NB, 256, 0, stream>>>(histG, btot);
    place_kernel<<<P, 256, 0, stream>>>(ei, histG, btot, bkt);
    bucket_fill_kernel<<<NB, 256, 0, stream>>>(btot, bkt, csr, offpk);

    // layer 1 (root = bf16 x in featb; in-place featb output is block-local)
    gather_kernel<<<GATHER_BLOCKS, 256, 0, stream>>>(featb, offpk, csr, aggb);
    layer_v4<<<TILE_BLOCKS, 256, 0, stream>>>(aggb, featb, wpk, b1, featb);

    // layer 2
    gather_kernel<<<GATHER_BLOCKS, 256, 0, stream>>>(featb, offpk, csr, aggb);
    layer_v4<<<TILE_BLOCKS, 256, 0, stream>>>(aggb, featb, wpk + 8192, b2, featb);

    // layer 3
    gather_kernel<<<GATHER_BLOCKS, 256, 0, stream>>>(featb, offpk, csr, aggb);
    layer_v4<<<TILE_BLOCKS, 256, 0, stream>>>(aggb, featb, wpk + 16384, b3, featb);

    // head
    head_v2<<<TILE_BLOCKS, 256, 0, stream>>>(featb, Wlin, blin, out);
}

// Round 5
// 295.749 us; speedup vs baseline: 1.3717x; 1.0232x over previous
//
#include <hip/hip_runtime.h>
#include <hip/hip_bf16.h>

#define N_NODES 100000
#define N_EDGES 1600000
#define HID 64
#define OUT_CH 32

// Deterministic radix partition into dst buckets. Zero global atomics
// (R5: contended global cursors serialize device-wide at ~6 ns/atomic).
// R12 lesson: don't fuse fat-LDS GEMM onto the latency-bound gather.
// R1/R2 lesson: channel-chunked L2-resident gather LOSES to monolithic
// (request-rate bound: chunking doubles request count, quadruples csr reads).
// R3 lesson: per-block scattered scalar weight loads cost ~8 us/layer ->
// pre-swizzle once. This round: fuse head into layer3, wprep into convhist.
#define NB 196           // ceil(100000/512) buckets of 512 consecutive dst nodes
#define P 1024           // partition blocks
#define EPP ((N_EDGES + P - 1) / P)   // 1563 edges per block
#define BKCAP 10240      // LDS csr staging cap (bucket mean 8192, sigma ~90)
#define MP 72            // bf16 tile pitch for MFMA layer (16B-aligned rows)

typedef unsigned short ushort_t;
typedef short bf16x8 __attribute__((ext_vector_type(8)));
typedef float f32x4 __attribute__((ext_vector_type(4)));

// bf16 helpers (RNE)
__device__ __forceinline__ ushort_t f2b(float f) {
    union { float f; unsigned u; } un; un.f = f;
    unsigned r = un.u + 0x7FFF + ((un.u >> 16) & 1);
    return (ushort_t)(r >> 16);
}
__device__ __forceinline__ float b2f(ushort_t u) {
    union { unsigned u; float f; } un; un.u = ((unsigned)u) << 16;
    return un.f;
}
__device__ __forceinline__ float blo(unsigned u) {
    union { unsigned u; float f; } un; un.u = u << 16; return un.f;
}
__device__ __forceinline__ float bhi(unsigned u) {
    union { unsigned u; float f; } un; un.u = u & 0xFFFF0000u; return un.f;
}

__device__ __forceinline__ int get_dst(const int* __restrict__ ei, int is64, int e) {
    return is64 ? ((const int2*)ei)[N_EDGES + e].x : ei[N_EDGES + e];
}
__device__ __forceinline__ int get_src(const int* __restrict__ ei, int is64, int e) {
    return is64 ? ((const int2*)ei)[e].x : ei[e];
}

// inline edge-dtype probe: int64 => odd 32-bit words all 0 (first wave)
__device__ __forceinline__ void detect_is64(const int* __restrict__ ei,
                                            int* __restrict__ sflag, int tid) {
    if (tid < 64) {
        int v = ei[2 * tid + 1];
        unsigned long long ball = __ballot(v == 0);
        if (tid == 0) *sflag = (ball == ~0ull) ? 1 : 0;
    }
}

// ---- convert x -> bf16 + bucket histograms (blocks <P) + weight swizzle ---
// Blocks [0, CONV_BLOCKS): feature conversion; blocks < P also histogram.
// Blocks [CONV_BLOCKS, CONV_BLOCKS+6): swizzle one weight matrix each into
// MFMA B-fragment order bf16 (fused former wprep_kernel; saves a launch).
// Fragment order: idx = ((nt*2+ks)*64 + lane)*8 + j <- W[k*HID+n],
// k = ks*32+(lane>>4)*8+j, n = nt*16+(lane&15).
#define CONV_BLOCKS ((N_NODES * HID / 4) / 256)   // 6250
__global__ void __launch_bounds__(256) convhist_kernel(
        const float* __restrict__ x, ushort_t* __restrict__ xb,
        const int* __restrict__ ei, int* __restrict__ histG,
        const float* __restrict__ W0, const float* __restrict__ W1,
        const float* __restrict__ W2, const float* __restrict__ W3,
        const float* __restrict__ W4, const float* __restrict__ W5,
        ushort_t* __restrict__ wpk) {
    int bid = blockIdx.x;
    if (bid >= CONV_BLOCKS) {        // weight-swizzle blocks
        const float* Ws[6] = {W0, W1, W2, W3, W4, W5};
        int w = bid - CONV_BLOCKS;
        const float* W = Ws[w];
        ushort_t* d = wpk + w * 4096;
        for (int idx = threadIdx.x; idx < 4096; idx += 256) {
            int j = idx & 7;
            int ln = (idx >> 3) & 63;
            int t = idx >> 9;            // nt*2+ks
            int ks = t & 1, nt = t >> 1;
            int k = ks * 32 + (ln >> 4) * 8 + j;
            int n = nt * 16 + (ln & 15);
            d[idx] = f2b(W[k * HID + n]);
        }
        return;
    }
    int i = bid * 256 + threadIdx.x;
    if (i < N_NODES * HID / 4) {
        float4 v = ((const float4*)x)[i];
        ushort4 o;
        o.x = f2b(v.x); o.y = f2b(v.y); o.z = f2b(v.z); o.w = f2b(v.w);
        ((ushort4*)xb)[i] = o;
    }
    if (bid >= P) return;
    __shared__ int sflag;
    __shared__ int lh[NB];
    int tid = threadIdx.x;
    detect_is64(ei, &sflag, tid);
    for (int k = tid; k < NB; k += 256) lh[k] = 0;
    __syncthreads();
    int is64 = sflag;
    int e0 = bid * EPP;
    int e1 = min(e0 + EPP, N_EDGES);
    for (int e = e0 + tid; e < e1; e += 256) {
        int d = get_dst(ei, is64, e);
        atomicAdd(&lh[d >> 9], 1);
    }
    __syncthreads();
    for (int k = tid; k < NB; k += 256) histG[k * P + bid] = lh[k];
}

// ---- per-bucket exclusive scan over P block-counts (4 elems/thread) -------
__global__ void __launch_bounds__(256) scan_kernel(int* __restrict__ histG,
                                                   int* __restrict__ btot) {
    __shared__ int ps[256];
    int b = blockIdx.x;
    int tid = threadIdx.x;
    int base4 = b * P + 4 * tid;
    int v0 = histG[base4], v1 = histG[base4 + 1], v2 = histG[base4 + 2], v3 = histG[base4 + 3];
    int pv = v0 + v1 + v2 + v3;
    ps[tid] = pv;
    __syncthreads();
    for (int d = 1; d < 256; d <<= 1) {
        int t = (tid >= d) ? ps[tid - d] : 0;
        __syncthreads();
        ps[tid] += t;
        __syncthreads();
    }
    int e = ps[tid] - pv;
    histG[base4] = e; e += v0;
    histG[base4 + 1] = e; e += v1;
    histG[base4 + 2] = e; e += v2;
    histG[base4 + 3] = e;
    if (tid == 255) btot[b] = ps[255];
}

// ---- place records at deterministic offsets (LDS cursors only) ------------
// Bucket bases from local 196-wide scan of btot. record = (dst&511)<<17 | src
__global__ void __launch_bounds__(256) place_kernel(
        const int* __restrict__ ei, const int* __restrict__ histG,
        const int* __restrict__ btot, int* __restrict__ bkt) {
    __shared__ int lcur[NB];
    __shared__ int ss[256];
    __shared__ int sflag;
    int tid = threadIdx.x;
    detect_is64(ei, &sflag, tid);
    int v = (tid < NB) ? btot[tid] : 0;
    ss[tid] = v;
    __syncthreads();
    for (int d = 1; d < 256; d <<= 1) {
        int t = (tid >= d) ? ss[tid - d] : 0;
        __syncthreads();
        ss[tid] += t;
        __syncthreads();
    }
    if (tid < NB) lcur[tid] = (ss[tid] - v) + histG[tid * P + blockIdx.x];
    __syncthreads();
    int is64 = sflag;
    int e0 = blockIdx.x * EPP;
    int e1 = min(e0 + EPP, N_EDGES);
    for (int e = e0 + tid; e < e1; e += 256) {
        int s = get_src(ei, is64, e);
        int d = get_dst(ei, is64, e);
        int val = ((d & 511) << 17) | s;
        int p = atomicAdd(&lcur[d >> 9], 1);
        bkt[p] = val;
    }
}

// ---- per-bucket csr build in LDS + packed off|deg -------------------------
// offpk[n] = (abs_off & 0x1FFFFF) | (deg << 21); bucket base from local scan.
__global__ void __launch_bounds__(256) bucket_fill_kernel(
        const int* __restrict__ btot, const int* __restrict__ bkt,
        int* __restrict__ csr, unsigned int* __restrict__ offpk) {
    __shared__ int lcnt[512];
    __shared__ int loff[512];
    __shared__ int lcur[512];
    __shared__ int ps[256];
    __shared__ int scsr[BKCAP];
    __shared__ int sbase;
    int b = blockIdx.x;
    int tid = threadIdx.x;
    int m = btot[b];
    int vb = (tid < NB) ? btot[tid] : 0;
    ps[tid] = vb;
    __syncthreads();
    for (int d = 1; d < 256; d <<= 1) {
        int t = (tid >= d) ? ps[tid - d] : 0;
        __syncthreads();
        ps[tid] += t;
        __syncthreads();
    }
    if (tid == b) sbase = ps[tid] - vb;   // exclusive prefix at b
    __syncthreads();
    int base = sbase;
    int n0 = b << 9;
    int nn = min(512, N_NODES - n0);

    lcnt[tid] = 0;
    lcnt[tid + 256] = 0;
    __syncthreads();
    for (int i = tid; i < m; i += 256) atomicAdd(&lcnt[bkt[base + i] >> 17], 1);
    __syncthreads();
    int a0 = lcnt[2 * tid], a1 = lcnt[2 * tid + 1];
    int pv = a0 + a1;
    ps[tid] = pv;
    __syncthreads();
    for (int d = 1; d < 256; d <<= 1) {
        int t = (tid >= d) ? ps[tid - d] : 0;
        __syncthreads();
        ps[tid] += t;
        __syncthreads();
    }
    int excl = ps[tid] - pv;
    loff[2 * tid] = excl;
    loff[2 * tid + 1] = excl + a0;
    lcur[2 * tid] = excl;
    lcur[2 * tid + 1] = excl + a0;
    __syncthreads();
    bool fit = (m <= BKCAP);
    for (int i = tid; i < m; i += 256) {
        int val = bkt[base + i];
        int dl = val >> 17;
        int p = atomicAdd(&lcur[dl], 1);
        if (fit) scsr[p] = val & 0x1FFFF;
        else csr[base + p] = val & 0x1FFFF;
    }
    __syncthreads();
    if (fit)
        for (int i = tid; i < m; i += 256) csr[base + i] = scsr[i];
    for (int i = tid; i < nn; i += 256)
        offpk[n0 + i] = (unsigned int)((base + loff[i]) | (lcnt[i] << 21));
}

// ---- gather: 4 edges per wave-iter, 16-deep unroll (4 int2 loads/lane) ----
__global__ void __launch_bounds__(256) gather_kernel(
        const ushort_t* __restrict__ hb, const unsigned int* __restrict__ offpk,
        const int* __restrict__ csr, ushort_t* __restrict__ aggb) {
    int node = blockIdx.x * 4 + (threadIdx.x >> 6);
    if (node >= N_NODES) return;
    int o = threadIdx.x & 63;
    int q4 = o >> 4;          // quarter 0..3 = edge slot
    int l = o & 15;           // channel group 4l..4l+3
    unsigned int v = offpk[node];
    int off0 = (int)(v & 0x1FFFFFu);
    int cnt = (int)(v >> 21);
    float a0 = 0.f, a1 = 0.f, a2 = 0.f, a3 = 0.f;
    int base = off0;
    int rem = cnt;
    while (rem > 0) {
        int take = min(rem, 64);
        int idxv = (o < take) ? csr[base + o] : 0;
        int j = 0;
        for (; j + 16 <= take; j += 16) {
            int i0 = __shfl(idxv, j + q4);
            int i1 = __shfl(idxv, j + 4 + q4);
            int i2 = __shfl(idxv, j + 8 + q4);
            int i3 = __shfl(idxv, j + 12 + q4);
            int2 u0 = ((const int2*)(hb + (size_t)i0 * HID))[l];
            int2 u1 = ((const int2*)(hb + (size_t)i1 * HID))[l];
            int2 u2 = ((const int2*)(hb + (size_t)i2 * HID))[l];
            int2 u3 = ((const int2*)(hb + (size_t)i3 * HID))[l];
            a0 += (blo(u0.x) + blo(u1.x)) + (blo(u2.x) + blo(u3.x));
            a1 += (bhi(u0.x) + bhi(u1.x)) + (bhi(u2.x) + bhi(u3.x));
            a2 += (blo(u0.y) + blo(u1.y)) + (blo(u2.y) + blo(u3.y));
            a3 += (bhi(u0.y) + bhi(u1.y)) + (bhi(u2.y) + bhi(u3.y));
        }
        for (; j < take; j += 4) {
            int e = j + q4;
            bool valid = (e < take);
            int idx = __shfl(idxv, valid ? e : 0);
            if (valid) {
                int2 u = ((const int2*)(hb + (size_t)idx * HID))[l];
                a0 += blo(u.x); a1 += bhi(u.x);
                a2 += blo(u.y); a3 += bhi(u.y);
            }
        }
        base += take;
        rem -= take;
    }
    a0 += __shfl_xor(a0, 16); a0 += __shfl_xor(a0, 32);
    a1 += __shfl_xor(a1, 16); a1 += __shfl_xor(a1, 32);
    a2 += __shfl_xor(a2, 16); a2 += __shfl_xor(a2, 32);
    a3 += __shfl_xor(a3, 16); a3 += __shfl_xor(a3, 32);
    if (o < 16) {
        float inv = 1.f / fmaxf((float)cnt, 1.f);
        ushort4 w;
        w.x = f2b(a0 * inv); w.y = f2b(a1 * inv);
        w.z = f2b(a2 * inv); w.w = f2b(a3 * inv);
        *(ushort4*)(aggb + (size_t)node * HID + l * 4) = w;
    }
}

// ---- layer (MFMA): relu(agg@Wl + h@Wr + b) -> bf16 [ + fused head ] -------
// 16x16x32 bf16 MFMA. Weights arrive PRE-SWIZZLED in fragment order:
// contiguous coalesced int4 LDS copy. A/H tiles pitch 72 (16B-aligned rows).
// Wave w owns nodes w*16..w*16+15; 4 n-tiles x 4 MFMA.
// C/D layout (verified m89/m91): col=lane&15, row=quad*4+reg.
// FUSE_HEAD: layer-3 variant keeps h in LDS (no global h round-trip; saves
// 25.6 MB traffic + the head launch) and computes out = h@Wlin + blin with
// fp32 weights (identical numerics to the former head_v2 pass).
template <bool FUSE_HEAD>
__global__ void __launch_bounds__(256) layer_mfma(
        const ushort_t* __restrict__ aggb, const ushort_t* __restrict__ rootb,
        const ushort_t* __restrict__ wpk, const float* __restrict__ bias,
        ushort_t* __restrict__ outb,
        const float* __restrict__ Wlin, const float* __restrict__ blin,
        float* __restrict__ out) {
    __shared__ __align__(16) ushort_t sWlF[4096];
    __shared__ __align__(16) ushort_t sWrF[4096];
    __shared__ __align__(16) ushort_t sA[64 * MP];
    __shared__ __align__(16) ushort_t sH[64 * MP];
    __shared__ float sbias[HID];
    __shared__ float sWo[FUSE_HEAD ? HID * OUT_CH : 1];
    __shared__ float sbo[FUSE_HEAD ? OUT_CH : 1];
    int tid = threadIdx.x;
    {   // weights: pre-swizzled bf16, contiguous coalesced int4 copy
        const int4* w4 = (const int4*)wpk;     // Wl: 512 int4, Wr: 512 int4
        int4* sl4 = (int4*)sWlF;
        int4* sr4 = (int4*)sWrF;
#pragma unroll
        for (int p = 0; p < 2; ++p) {
            int i = tid + 256 * p;
            sl4[i] = w4[i];
            sr4[i] = w4[512 + i];
        }
    }
    if (tid < HID) sbias[tid] = bias[tid];
    size_t tbase = (size_t)blockIdx.x * 64 * HID;
    {   // 512 int4 chunks, 2 per thread (overread lands in slack)
        const int4* ga = (const int4*)(aggb + tbase);
        const int4* gh = (const int4*)(rootb + tbase);
#pragma unroll
        for (int p = 0; p < 2; ++p) {
            int q = tid + 256 * p;
            int r = q >> 3, u = q & 7;
            *(int4*)(sA + r * MP + u * 8) = ga[q];
            *(int4*)(sH + r * MP + u * 8) = gh[q];
        }
    }
    __syncthreads();

    int wave = tid >> 6, lane = tid & 63;
    int quad = lane >> 4, col = lane & 15;
    int arow = wave * 16 + col;
    bf16x8 aA0 = *(const bf16x8*)(sA + arow * MP + quad * 8);
    bf16x8 aA1 = *(const bf16x8*)(sA + arow * MP + 32 + quad * 8);
    bf16x8 aH0 = *(const bf16x8*)(sH + arow * MP + quad * 8);
    bf16x8 aH1 = *(const bf16x8*)(sH + arow * MP + 32 + quad * 8);
    int node0 = blockIdx.x * 64;
    ushort_t hv[4][4];   // bf16 h for FUSE_HEAD path: [nt][r]
#pragma unroll
    for (int nt = 0; nt < 4; ++nt) {
        f32x4 acc = {0.f, 0.f, 0.f, 0.f};
        const bf16x8* bl = (const bf16x8*)(sWlF + nt * 1024);
        const bf16x8* br = (const bf16x8*)(sWrF + nt * 1024);
        acc = __builtin_amdgcn_mfma_f32_16x16x32_bf16(aA0, bl[lane], acc, 0, 0, 0);
        acc = __builtin_amdgcn_mfma_f32_16x16x32_bf16(aA1, bl[64 + lane], acc, 0, 0, 0);
        acc = __builtin_amdgcn_mfma_f32_16x16x32_bf16(aH0, br[lane], acc, 0, 0, 0);
        acc = __builtin_amdgcn_mfma_f32_16x16x32_bf16(aH1, br[64 + lane], acc, 0, 0, 0);
        float bv = sbias[nt * 16 + col];
#pragma unroll
        for (int r = 0; r < 4; ++r) {
            ushort_t hb16 = f2b(fmaxf(acc[r] + bv, 0.f));
            if constexpr (FUSE_HEAD) {
                hv[nt][r] = hb16;
            } else {
                int n = node0 + wave * 16 + quad * 4 + r;
                if (n < N_NODES)
                    outb[(size_t)n * HID + nt * 16 + col] = hb16;
            }
        }
    }

    if constexpr (FUSE_HEAD) {
        // all fragment reads + MFMAs are done; repurpose sA for the h tile
        __syncthreads();
#pragma unroll
        for (int nt = 0; nt < 4; ++nt)
#pragma unroll
            for (int r = 0; r < 4; ++r)
                sA[(wave * 16 + quad * 4 + r) * MP + nt * 16 + col] = hv[nt][r];
        {   // stage Wlin (fp32, 2048 floats = 512 int4) + blin
            const int4* W4 = (const int4*)Wlin;
            int4* sW4 = (int4*)sWo;
#pragma unroll
            for (int p = 0; p < 2; ++p) sW4[tid + 256 * p] = W4[tid + 256 * p];
            if (tid < OUT_CH) sbo[tid] = blin[tid];
        }
        __syncthreads();

        int c0 = (tid & 7) << 2;
        int n0 = (tid >> 3) << 1;
        float acc2[2][4];
#pragma unroll
        for (int i = 0; i < 2; ++i)
#pragma unroll
            for (int j = 0; j < 4; ++j) acc2[i][j] = sbo[c0 + j];

#pragma unroll 4
        for (int kk = 0; kk < 32; ++kk) {
            float4 w0 = *(const float4*)&sWo[(2 * kk) * OUT_CH + c0];
            float4 w1 = *(const float4*)&sWo[(2 * kk + 1) * OUT_CH + c0];
            const float* w0p = (const float*)&w0;
            const float* w1p = (const float*)&w1;
#pragma unroll
            for (int i = 0; i < 2; ++i) {
                unsigned uh = *(const unsigned*)(sA + (n0 + i) * MP + 2 * kk);
                float h0 = blo(uh), h1 = bhi(uh);
#pragma unroll
                for (int j = 0; j < 4; ++j) acc2[i][j] += h0 * w0p[j] + h1 * w1p[j];
            }
        }

#pragma unroll
        for (int i = 0; i < 2; ++i) {
            int n = node0 + n0 + i;
            if (n < N_NODES) {
                float4 o4;
                o4.x = acc2[i][0]; o4.y = acc2[i][1];
                o4.z = acc2[i][2]; o4.w = acc2[i][3];
                *(float4*)(out + (size_t)n * OUT_CH + c0) = o4;
            }
        }
    }
}

extern "C" void kernel_launch(void* const* d_in, const int* in_sizes, int n_in,
                              void* d_out, int out_size, void* d_ws, size_t ws_size,
                              hipStream_t stream) {
    const float* x    = (const float*)d_in[0];
    const int*   ei   = (const int*)d_in[1];
    const float* Wl1  = (const float*)d_in[2];
    const float* Wr1  = (const float*)d_in[3];
    const float* b1   = (const float*)d_in[4];
    const float* Wl2  = (const float*)d_in[5];
    const float* Wr2  = (const float*)d_in[6];
    const float* b2   = (const float*)d_in[7];
    const float* Wl3  = (const float*)d_in[8];
    const float* Wr3  = (const float*)d_in[9];
    const float* b3   = (const float*)d_in[10];
    const float* Wlin = (const float*)d_in[11];
    const float* blin = (const float*)d_in[12];
    float* out = (float*)d_out;

    // workspace layout (4-byte units), ~33 MB; tile overreads land in slack.
    int* ip              = (int*)d_ws;
    unsigned int* offpk  = (unsigned int*)ip;           // 100096
    int* btot            = (int*)(offpk + 100096);      // 256
    int* histG           = btot + 256;                  // NB*P = 200704
    int* csr             = histG + NB * P;              // 1600000
    ushort_t* aggb       = (ushort_t*)(csr + N_EDGES);  // 6.4M bf16 + 8192 slack
    ushort_t* featb      = aggb + 6408192;              // 6.4M bf16 + 8192 slack
    ushort_t* wpk        = featb + 6408192;             // 6*4096 pre-swizzled weights
    int* bkt             = (int*)aggb;  // bucket records alias aggb (dead until gather)

    const int GATHER_BLOCKS = (N_NODES + 3) / 4;         // 25000
    const int TILE_BLOCKS   = (N_NODES + 63) / 64;       // 1563

    // CSR build (+fused weight swizzle): convert+hist+wprep, scan, place,
    // per-bucket fill
    convhist_kernel<<<CONV_BLOCKS + 6, 256, 0, stream>>>(
        x, featb, ei, histG, Wl1, Wr1, Wl2, Wr2, Wl3, Wr3, wpk);
    scan_kernel<<<NB, 256, 0, stream>>>(histG, btot);
    place_kernel<<<P, 256, 0, stream>>>(ei, histG, btot, bkt);
    bucket_fill_kernel<<<NB, 256, 0, stream>>>(btot, bkt, csr, offpk);

    // layer 1 (root = bf16 x in featb; in-place featb output is block-local)
    gather_kernel<<<GATHER_BLOCKS, 256, 0, stream>>>(featb, offpk, csr, aggb);
    layer_mfma<false><<<TILE_BLOCKS, 256, 0, stream>>>(
        aggb, featb, wpk, b1, featb, nullptr, nullptr, nullptr);

    // layer 2
    gather_kernel<<<GATHER_BLOCKS, 256, 0, stream>>>(featb, offpk, csr, aggb);
    layer_mfma<false><<<TILE_BLOCKS, 256, 0, stream>>>(
        aggb, featb, wpk + 8192, b2, featb, nullptr, nullptr, nullptr);

    // layer 3 + fused head (h never leaves the block)
    gather_kernel<<<GATHER_BLOCKS, 256, 0, stream>>>(featb, offpk, csr, aggb);
    layer_mfma<true><<<TILE_BLOCKS, 256, 0, stream>>>(
        aggb, featb, wpk + 16384, b3, nullptr, Wlin, blin, out);
}

// Round 6
// 260.014 us; speedup vs baseline: 1.5602x; 1.1374x over previous
//
#include <hip/hip_runtime.h>
#include <hip/hip_bf16.h>

#define N_NODES 100000
#define N_EDGES 1600000
#define HID 64
#define OUT_CH 32

// Deterministic radix partition into dst buckets. Zero global atomics
// (R5: contended global cursors serialize device-wide at ~6 ns/atomic).
// R12 lesson: don't fuse fat-LDS GEMM onto the latency-bound gather.
// R1/R2 lesson: channel-chunked L2-resident gather LOSES to monolithic
// (request-rate bound: chunking doubles request count, quadruples csr reads).
// R3 lesson: per-block scattered scalar weight loads cost ~8 us/layer ->
// pre-swizzle once. R5 lesson: head fused into layer3 (-7 us).
// This round: gather MLP-deepening (16 int4 loads in flight per lane,
// lane-owned channels -> no cross-lane reduction).
#define NB 196           // ceil(100000/512) buckets of 512 consecutive dst nodes
#define P 1024           // partition blocks
#define EPP ((N_EDGES + P - 1) / P)   // 1563 edges per block
#define BKCAP 10240      // LDS csr staging cap (bucket mean 8192, sigma ~90)
#define MP 72            // bf16 tile pitch for MFMA layer (16B-aligned rows)

typedef unsigned short ushort_t;
typedef short bf16x8 __attribute__((ext_vector_type(8)));
typedef float f32x4 __attribute__((ext_vector_type(4)));

// bf16 helpers (RNE)
__device__ __forceinline__ ushort_t f2b(float f) {
    union { float f; unsigned u; } un; un.f = f;
    unsigned r = un.u + 0x7FFF + ((un.u >> 16) & 1);
    return (ushort_t)(r >> 16);
}
__device__ __forceinline__ float b2f(ushort_t u) {
    union { unsigned u; float f; } un; un.u = ((unsigned)u) << 16;
    return un.f;
}
__device__ __forceinline__ float blo(unsigned u) {
    union { unsigned u; float f; } un; un.u = u << 16; return un.f;
}
__device__ __forceinline__ float bhi(unsigned u) {
    union { unsigned u; float f; } un; un.u = u & 0xFFFF0000u; return un.f;
}

__device__ __forceinline__ int get_dst(const int* __restrict__ ei, int is64, int e) {
    return is64 ? ((const int2*)ei)[N_EDGES + e].x : ei[N_EDGES + e];
}
__device__ __forceinline__ int get_src(const int* __restrict__ ei, int is64, int e) {
    return is64 ? ((const int2*)ei)[e].x : ei[e];
}

// inline edge-dtype probe: int64 => odd 32-bit words all 0 (first wave)
__device__ __forceinline__ void detect_is64(const int* __restrict__ ei,
                                            int* __restrict__ sflag, int tid) {
    if (tid < 64) {
        int v = ei[2 * tid + 1];
        unsigned long long ball = __ballot(v == 0);
        if (tid == 0) *sflag = (ball == ~0ull) ? 1 : 0;
    }
}

// ---- convert x -> bf16 + bucket histograms (blocks <P) + weight swizzle ---
// Blocks [0, CONV_BLOCKS): feature conversion; blocks < P also histogram.
// Blocks [CONV_BLOCKS, CONV_BLOCKS+6): swizzle one weight matrix each into
// MFMA B-fragment order bf16 (fused former wprep_kernel; saves a launch).
// Fragment order: idx = ((nt*2+ks)*64 + lane)*8 + j <- W[k*HID+n],
// k = ks*32+(lane>>4)*8+j, n = nt*16+(lane&15).
#define CONV_BLOCKS ((N_NODES * HID / 4) / 256)   // 6250
__global__ void __launch_bounds__(256) convhist_kernel(
        const float* __restrict__ x, ushort_t* __restrict__ xb,
        const int* __restrict__ ei, int* __restrict__ histG,
        const float* __restrict__ W0, const float* __restrict__ W1,
        const float* __restrict__ W2, const float* __restrict__ W3,
        const float* __restrict__ W4, const float* __restrict__ W5,
        ushort_t* __restrict__ wpk) {
    int bid = blockIdx.x;
    if (bid >= CONV_BLOCKS) {        // weight-swizzle blocks
        const float* Ws[6] = {W0, W1, W2, W3, W4, W5};
        int w = bid - CONV_BLOCKS;
        const float* W = Ws[w];
        ushort_t* d = wpk + w * 4096;
        for (int idx = threadIdx.x; idx < 4096; idx += 256) {
            int j = idx & 7;
            int ln = (idx >> 3) & 63;
            int t = idx >> 9;            // nt*2+ks
            int ks = t & 1, nt = t >> 1;
            int k = ks * 32 + (ln >> 4) * 8 + j;
            int n = nt * 16 + (ln & 15);
            d[idx] = f2b(W[k * HID + n]);
        }
        return;
    }
    int i = bid * 256 + threadIdx.x;
    if (i < N_NODES * HID / 4) {
        float4 v = ((const float4*)x)[i];
        ushort4 o;
        o.x = f2b(v.x); o.y = f2b(v.y); o.z = f2b(v.z); o.w = f2b(v.w);
        ((ushort4*)xb)[i] = o;
    }
    if (bid >= P) return;
    __shared__ int sflag;
    __shared__ int lh[NB];
    int tid = threadIdx.x;
    detect_is64(ei, &sflag, tid);
    for (int k = tid; k < NB; k += 256) lh[k] = 0;
    __syncthreads();
    int is64 = sflag;
    int e0 = bid * EPP;
    int e1 = min(e0 + EPP, N_EDGES);
    for (int e = e0 + tid; e < e1; e += 256) {
        int d = get_dst(ei, is64, e);
        atomicAdd(&lh[d >> 9], 1);
    }
    __syncthreads();
    for (int k = tid; k < NB; k += 256) histG[k * P + bid] = lh[k];
}

// ---- per-bucket exclusive scan over P block-counts (4 elems/thread) -------
__global__ void __launch_bounds__(256) scan_kernel(int* __restrict__ histG,
                                                   int* __restrict__ btot) {
    __shared__ int ps[256];
    int b = blockIdx.x;
    int tid = threadIdx.x;
    int base4 = b * P + 4 * tid;
    int v0 = histG[base4], v1 = histG[base4 + 1], v2 = histG[base4 + 2], v3 = histG[base4 + 3];
    int pv = v0 + v1 + v2 + v3;
    ps[tid] = pv;
    __syncthreads();
    for (int d = 1; d < 256; d <<= 1) {
        int t = (tid >= d) ? ps[tid - d] : 0;
        __syncthreads();
        ps[tid] += t;
        __syncthreads();
    }
    int e = ps[tid] - pv;
    histG[base4] = e; e += v0;
    histG[base4 + 1] = e; e += v1;
    histG[base4 + 2] = e; e += v2;
    histG[base4 + 3] = e;
    if (tid == 255) btot[b] = ps[255];
}

// ---- place records at deterministic offsets (LDS cursors only) ------------
// Bucket bases from local 196-wide scan of btot. record = (dst&511)<<17 | src
__global__ void __launch_bounds__(256) place_kernel(
        const int* __restrict__ ei, const int* __restrict__ histG,
        const int* __restrict__ btot, int* __restrict__ bkt) {
    __shared__ int lcur[NB];
    __shared__ int ss[256];
    __shared__ int sflag;
    int tid = threadIdx.x;
    detect_is64(ei, &sflag, tid);
    int v = (tid < NB) ? btot[tid] : 0;
    ss[tid] = v;
    __syncthreads();
    for (int d = 1; d < 256; d <<= 1) {
        int t = (tid >= d) ? ss[tid - d] : 0;
        __syncthreads();
        ss[tid] += t;
        __syncthreads();
    }
    if (tid < NB) lcur[tid] = (ss[tid] - v) + histG[tid * P + blockIdx.x];
    __syncthreads();
    int is64 = sflag;
    int e0 = blockIdx.x * EPP;
    int e1 = min(e0 + EPP, N_EDGES);
    for (int e = e0 + tid; e < e1; e += 256) {
        int s = get_src(ei, is64, e);
        int d = get_dst(ei, is64, e);
        int val = ((d & 511) << 17) | s;
        int p = atomicAdd(&lcur[d >> 9], 1);
        bkt[p] = val;
    }
}

// ---- per-bucket csr build in LDS + packed off|deg -------------------------
// offpk[n] = (abs_off & 0x1FFFFF) | (deg << 21); bucket base from local scan.
__global__ void __launch_bounds__(256) bucket_fill_kernel(
        const int* __restrict__ btot, const int* __restrict__ bkt,
        int* __restrict__ csr, unsigned int* __restrict__ offpk) {
    __shared__ int lcnt[512];
    __shared__ int loff[512];
    __shared__ int lcur[512];
    __shared__ int ps[256];
    __shared__ int scsr[BKCAP];
    __shared__ int sbase;
    int b = blockIdx.x;
    int tid = threadIdx.x;
    int m = btot[b];
    int vb = (tid < NB) ? btot[tid] : 0;
    ps[tid] = vb;
    __syncthreads();
    for (int d = 1; d < 256; d <<= 1) {
        int t = (tid >= d) ? ps[tid - d] : 0;
        __syncthreads();
        ps[tid] += t;
        __syncthreads();
    }
    if (tid == b) sbase = ps[tid] - vb;   // exclusive prefix at b
    __syncthreads();
    int base = sbase;
    int n0 = b << 9;
    int nn = min(512, N_NODES - n0);

    lcnt[tid] = 0;
    lcnt[tid + 256] = 0;
    __syncthreads();
    for (int i = tid; i < m; i += 256) atomicAdd(&lcnt[bkt[base + i] >> 17], 1);
    __syncthreads();
    int a0 = lcnt[2 * tid], a1 = lcnt[2 * tid + 1];
    int pv = a0 + a1;
    ps[tid] = pv;
    __syncthreads();
    for (int d = 1; d < 256; d <<= 1) {
        int t = (tid >= d) ? ps[tid - d] : 0;
        __syncthreads();
        ps[tid] += t;
        __syncthreads();
    }
    int excl = ps[tid] - pv;
    loff[2 * tid] = excl;
    loff[2 * tid + 1] = excl + a0;
    lcur[2 * tid] = excl;
    lcur[2 * tid + 1] = excl + a0;
    __syncthreads();
    bool fit = (m <= BKCAP);
    for (int i = tid; i < m; i += 256) {
        int val = bkt[base + i];
        int dl = val >> 17;
        int p = atomicAdd(&lcur[dl], 1);
        if (fit) scsr[p] = val & 0x1FFFF;
        else csr[base + p] = val & 0x1FFFF;
    }
    __syncthreads();
    if (fit)
        for (int i = tid; i < m; i += 256) csr[base + i] = scsr[i];
    for (int i = tid; i < nn; i += 256)
        offpk[n0 + i] = (unsigned int)((base + loff[i]) | (lcnt[i] << 21));
}

// ---- gather v2: 8 lanes/node, int4 loads, 16 edges in flight per lane -----
// Lane l of a node's 8-lane group owns channels 8l..8l+7 exclusively:
// NO cross-lane reduction. Per 16-edge batch: 2 guarded csr loads/lane,
// shfl-distribute, 16 independent int4 row loads (16 KB in flight per wave
// vs 2 KB in the old 16-lane/int2 form -> 4x memory-level parallelism on
// the ~700cy LLC hits that bound this kernel). Invalid slots read row 0
// (L1-hot) and are zeroed before accumulation.
__global__ void __launch_bounds__(256) gather_kernel(
        const ushort_t* __restrict__ hb, const unsigned int* __restrict__ offpk,
        const int* __restrict__ csr, ushort_t* __restrict__ aggb) {
    int tid = threadIdx.x;
    int wv = tid >> 6, ln = tid & 63;
    int g = ln >> 3;          // node sub-group 0..7 within wave
    int l = ln & 7;           // 16B channel slot: channels 8l..8l+7
    int node = blockIdx.x * 32 + wv * 8 + g;   // 3125*32 = 100000 exact
    unsigned int v = offpk[node];
    int off = (int)(v & 0x1FFFFFu);
    int cnt = (int)(v >> 21);
    float a0 = 0.f, a1 = 0.f, a2 = 0.f, a3 = 0.f;
    float a4 = 0.f, a5 = 0.f, a6 = 0.f, a7 = 0.f;
    int gbase = g << 3;
    for (int b = 0; b < cnt; b += 16) {
        int rem = cnt - b;
        int e0 = (l < rem) ? csr[off + b + l] : 0;
        int e1 = (l + 8 < rem) ? csr[off + b + 8 + l] : 0;
        int4 u[16];
#pragma unroll
        for (int j = 0; j < 8; ++j)
            u[j] = ((const int4*)(hb + (size_t)__shfl(e0, gbase + j) * HID))[l];
#pragma unroll
        for (int j = 0; j < 8; ++j)
            u[8 + j] = ((const int4*)(hb + (size_t)__shfl(e1, gbase + j) * HID))[l];
#pragma unroll
        for (int j = 0; j < 16; ++j) {
            if (j >= rem) { u[j].x = 0; u[j].y = 0; u[j].z = 0; u[j].w = 0; }
            a0 += blo(u[j].x); a1 += bhi(u[j].x);
            a2 += blo(u[j].y); a3 += bhi(u[j].y);
            a4 += blo(u[j].z); a5 += bhi(u[j].z);
            a6 += blo(u[j].w); a7 += bhi(u[j].w);
        }
    }
    float inv = 1.f / fmaxf((float)cnt, 1.f);
    int4 w;
    w.x = (int)((unsigned)f2b(a0 * inv) | ((unsigned)f2b(a1 * inv) << 16));
    w.y = (int)((unsigned)f2b(a2 * inv) | ((unsigned)f2b(a3 * inv) << 16));
    w.z = (int)((unsigned)f2b(a4 * inv) | ((unsigned)f2b(a5 * inv) << 16));
    w.w = (int)((unsigned)f2b(a6 * inv) | ((unsigned)f2b(a7 * inv) << 16));
    *(int4*)(aggb + (size_t)node * HID + l * 8) = w;
}

// ---- layer (MFMA): relu(agg@Wl + h@Wr + b) -> bf16 [ + fused head ] -------
// 16x16x32 bf16 MFMA. Weights arrive PRE-SWIZZLED in fragment order:
// contiguous coalesced int4 LDS copy. A/H tiles pitch 72 (16B-aligned rows).
// Wave w owns nodes w*16..w*16+15; 4 n-tiles x 4 MFMA.
// C/D layout (verified m89/m91): col=lane&15, row=quad*4+reg.
// FUSE_HEAD: layer-3 variant keeps h in LDS (no global h round-trip; saves
// 25.6 MB traffic + the head launch) and computes out = h@Wlin + blin with
// fp32 weights (identical numerics to the former head_v2 pass).
template <bool FUSE_HEAD>
__global__ void __launch_bounds__(256) layer_mfma(
        const ushort_t* __restrict__ aggb, const ushort_t* __restrict__ rootb,
        const ushort_t* __restrict__ wpk, const float* __restrict__ bias,
        ushort_t* __restrict__ outb,
        const float* __restrict__ Wlin, const float* __restrict__ blin,
        float* __restrict__ out) {
    __shared__ __align__(16) ushort_t sWlF[4096];
    __shared__ __align__(16) ushort_t sWrF[4096];
    __shared__ __align__(16) ushort_t sA[64 * MP];
    __shared__ __align__(16) ushort_t sH[64 * MP];
    __shared__ float sbias[HID];
    __shared__ float sWo[FUSE_HEAD ? HID * OUT_CH : 1];
    __shared__ float sbo[FUSE_HEAD ? OUT_CH : 1];
    int tid = threadIdx.x;
    {   // weights: pre-swizzled bf16, contiguous coalesced int4 copy
        const int4* w4 = (const int4*)wpk;     // Wl: 512 int4, Wr: 512 int4
        int4* sl4 = (int4*)sWlF;
        int4* sr4 = (int4*)sWrF;
#pragma unroll
        for (int p = 0; p < 2; ++p) {
            int i = tid + 256 * p;
            sl4[i] = w4[i];
            sr4[i] = w4[512 + i];
        }
    }
    if (tid < HID) sbias[tid] = bias[tid];
    size_t tbase = (size_t)blockIdx.x * 64 * HID;
    {   // 512 int4 chunks, 2 per thread (overread lands in slack)
        const int4* ga = (const int4*)(aggb + tbase);
        const int4* gh = (const int4*)(rootb + tbase);
#pragma unroll
        for (int p = 0; p < 2; ++p) {
            int q = tid + 256 * p;
            int r = q >> 3, u = q & 7;
            *(int4*)(sA + r * MP + u * 8) = ga[q];
            *(int4*)(sH + r * MP + u * 8) = gh[q];
        }
    }
    __syncthreads();

    int wave = tid >> 6, lane = tid & 63;
    int quad = lane >> 4, col = lane & 15;
    int arow = wave * 16 + col;
    bf16x8 aA0 = *(const bf16x8*)(sA + arow * MP + quad * 8);
    bf16x8 aA1 = *(const bf16x8*)(sA + arow * MP + 32 + quad * 8);
    bf16x8 aH0 = *(const bf16x8*)(sH + arow * MP + quad * 8);
    bf16x8 aH1 = *(const bf16x8*)(sH + arow * MP + 32 + quad * 8);
    int node0 = blockIdx.x * 64;
    ushort_t hv[4][4];   // bf16 h for FUSE_HEAD path: [nt][r]
#pragma unroll
    for (int nt = 0; nt < 4; ++nt) {
        f32x4 acc = {0.f, 0.f, 0.f, 0.f};
        const bf16x8* bl = (const bf16x8*)(sWlF + nt * 1024);
        const bf16x8* br = (const bf16x8*)(sWrF + nt * 1024);
        acc = __builtin_amdgcn_mfma_f32_16x16x32_bf16(aA0, bl[lane], acc, 0, 0, 0);
        acc = __builtin_amdgcn_mfma_f32_16x16x32_bf16(aA1, bl[64 + lane], acc, 0, 0, 0);
        acc = __builtin_amdgcn_mfma_f32_16x16x32_bf16(aH0, br[lane], acc, 0, 0, 0);
        acc = __builtin_amdgcn_mfma_f32_16x16x32_bf16(aH1, br[64 + lane], acc, 0, 0, 0);
        float bv = sbias[nt * 16 + col];
#pragma unroll
        for (int r = 0; r < 4; ++r) {
            ushort_t hb16 = f2b(fmaxf(acc[r] + bv, 0.f));
            if constexpr (FUSE_HEAD) {
                hv[nt][r] = hb16;
            } else {
                int n = node0 + wave * 16 + quad * 4 + r;
                if (n < N_NODES)
                    outb[(size_t)n * HID + nt * 16 + col] = hb16;
            }
        }
    }

    if constexpr (FUSE_HEAD) {
        // all fragment reads + MFMAs are done; repurpose sA for the h tile
        __syncthreads();
#pragma unroll
        for (int nt = 0; nt < 4; ++nt)
#pragma unroll
            for (int r = 0; r < 4; ++r)
                sA[(wave * 16 + quad * 4 + r) * MP + nt * 16 + col] = hv[nt][r];
        {   // stage Wlin (fp32, 2048 floats = 512 int4) + blin
            const int4* W4 = (const int4*)Wlin;
            int4* sW4 = (int4*)sWo;
#pragma unroll
            for (int p = 0; p < 2; ++p) sW4[tid + 256 * p] = W4[tid + 256 * p];
            if (tid < OUT_CH) sbo[tid] = blin[tid];
        }
        __syncthreads();

        int c0 = (tid & 7) << 2;
        int n0 = (tid >> 3) << 1;
        float acc2[2][4];
#pragma unroll
        for (int i = 0; i < 2; ++i)
#pragma unroll
            for (int j = 0; j < 4; ++j) acc2[i][j] = sbo[c0 + j];

#pragma unroll 4
        for (int kk = 0; kk < 32; ++kk) {
            float4 w0 = *(const float4*)&sWo[(2 * kk) * OUT_CH + c0];
            float4 w1 = *(const float4*)&sWo[(2 * kk + 1) * OUT_CH + c0];
            const float* w0p = (const float*)&w0;
            const float* w1p = (const float*)&w1;
#pragma unroll
            for (int i = 0; i < 2; ++i) {
                unsigned uh = *(const unsigned*)(sA + (n0 + i) * MP + 2 * kk);
                float h0 = blo(uh), h1 = bhi(uh);
#pragma unroll
                for (int j = 0; j < 4; ++j) acc2[i][j] += h0 * w0p[j] + h1 * w1p[j];
            }
        }

#pragma unroll
        for (int i = 0; i < 2; ++i) {
            int n = node0 + n0 + i;
            if (n < N_NODES) {
                float4 o4;
                o4.x = acc2[i][0]; o4.y = acc2[i][1];
                o4.z = acc2[i][2]; o4.w = acc2[i][3];
                *(float4*)(out + (size_t)n * OUT_CH + c0) = o4;
            }
        }
    }
}

extern "C" void kernel_launch(void* const* d_in, const int* in_sizes, int n_in,
                              void* d_out, int out_size, void* d_ws, size_t ws_size,
                              hipStream_t stream) {
    const float* x    = (const float*)d_in[0];
    const int*   ei   = (const int*)d_in[1];
    const float* Wl1  = (const float*)d_in[2];
    const float* Wr1  = (const float*)d_in[3];
    const float* b1   = (const float*)d_in[4];
    const float* Wl2  = (const float*)d_in[5];
    const float* Wr2  = (const float*)d_in[6];
    const float* b2   = (const float*)d_in[7];
    const float* Wl3  = (const float*)d_in[8];
    const float* Wr3  = (const float*)d_in[9];
    const float* b3   = (const float*)d_in[10];
    const float* Wlin = (const float*)d_in[11];
    const float* blin = (const float*)d_in[12];
    float* out = (float*)d_out;

    // workspace layout (4-byte units), ~33 MB; tile overreads land in slack.
    int* ip              = (int*)d_ws;
    unsigned int* offpk  = (unsigned int*)ip;           // 100096
    int* btot            = (int*)(offpk + 100096);      // 256
    int* histG           = btot + 256;                  // NB*P = 200704
    int* csr             = histG + NB * P;              // 1600000
    ushort_t* aggb       = (ushort_t*)(csr + N_EDGES);  // 6.4M bf16 + 8192 slack
    ushort_t* featb      = aggb + 6408192;              // 6.4M bf16 + 8192 slack
    ushort_t* wpk        = featb + 6408192;             // 6*4096 pre-swizzled weights
    int* bkt             = (int*)aggb;  // bucket records alias aggb (dead until gather)

    const int GATHER_BLOCKS = N_NODES / 32;              // 3125 (32 nodes/block)
    const int TILE_BLOCKS   = (N_NODES + 63) / 64;       // 1563

    // CSR build (+fused weight swizzle): convert+hist+wprep, scan, place,
    // per-bucket fill
    convhist_kernel<<<CONV_BLOCKS + 6, 256, 0, stream>>>(
        x, featb, ei, histG, Wl1, Wr1, Wl2, Wr2, Wl3, Wr3, wpk);
    scan_kernel<<<NB, 256, 0, stream>>>(histG, btot);
    place_kernel<<<P, 256, 0, stream>>>(ei, histG, btot, bkt);
    bucket_fill_kernel<<<NB, 256, 0, stream>>>(btot, bkt, csr, offpk);

    // layer 1 (root = bf16 x in featb; in-place featb output is block-local)
    gather_kernel<<<GATHER_BLOCKS, 256, 0, stream>>>(featb, offpk, csr, aggb);
    layer_mfma<false><<<TILE_BLOCKS, 256, 0, stream>>>(
        aggb, featb, wpk, b1, featb, nullptr, nullptr, nullptr);

    // layer 2
    gather_kernel<<<GATHER_BLOCKS, 256, 0, stream>>>(featb, offpk, csr, aggb);
    layer_mfma<false><<<TILE_BLOCKS, 256, 0, stream>>>(
        aggb, featb, wpk + 8192, b2, featb, nullptr, nullptr, nullptr);

    // layer 3 + fused head (h never leaves the block)
    gather_kernel<<<GATHER_BLOCKS, 256, 0, stream>>>(featb, offpk, csr, aggb);
    layer_mfma<true><<<TILE_BLOCKS, 256, 0, stream>>>(
        aggb, featb, wpk + 16384, b3, nullptr, Wlin, blin, out);
}